// Round 10
// baseline (415.081 us; speedup 1.0000x reference)
//
#include <hip/hip_runtime.h>

// ProbAttention on MI355X (gfx950). Inputs/outputs fp32; compute in bf16 MFMA
// (mfma_f32_16x16x32_bf16, fp32 accumulate). B=8, L=4096, D=512, H=8, DK=64,
// S=512, CONV_K=3, POOL=2.
//
// v11 — MEASUREMENT PROBE. v10 unchanged EXCEPT attn_fused is launched as
// FOUR grid-partition dispatches ((8,8,8) each, block-offset x0) instead of
// one (32,8,8). Blocks are independent, so this is semantically identical;
// each quarter runs ~33 us, vacating the top-5-by-duration display that ~130us
// attn reps were flooding, so the conv GEMM / dense / cvt durations become
// visible. Rationale: v10's gemm staging rewrite (predicted -35us) moved the
// pipeline by -2.4us (noise) — the 251us of non-attn time is unattributed and
// two rounds of theory failed to locate it. Measure, then optimize.

typedef __attribute__((ext_vector_type(8))) short  short8;
typedef __attribute__((ext_vector_type(4))) short  short4b;
typedef __attribute__((ext_vector_type(4))) float  f32x4;

#define LSEQ   4096
#define SK     512
#define EDIM   512
#define LPAD   4098            // L + 2
#define PADROW 2098176         // LPAD * 512 (shorts)
#define SCALE2 0.180336880f    // 0.125 * log2(e) — fp32 score scale for exp2

static __device__ __forceinline__ float bf2f(unsigned short h) {
    union { unsigned int u; float f; } v; v.u = ((unsigned int)h) << 16; return v.f;
}
static __device__ __forceinline__ unsigned short f2bf(float f) {
    union { float f; unsigned int u; } v; v.f = f;
    unsigned int r = (v.u + 0x7fffu + ((v.u >> 16) & 1u)) >> 16;
    return (unsigned short)r;
}
static __device__ __forceinline__ unsigned int cvt_pk_bf16(float lo, float hi) {
    unsigned int r;
    asm("v_cvt_pk_bf16_f32 %0, %1, %2" : "=v"(r) : "v"(lo), "v"(hi));
    return r;   // dst[15:0] = bf16(lo), dst[31:16] = bf16(hi)
}
// async global -> LDS, 16 B per lane; LDS dest = wave-uniform base + lane*16
typedef __attribute__((address_space(1))) const unsigned int  gu32;
typedef __attribute__((address_space(3))) unsigned int        lu32;
static __device__ __forceinline__ void g2l16(const unsigned short* g, unsigned short* l)
{
    __builtin_amdgcn_global_load_lds((gu32*)g, (lu32*)l, 16, 0, 0);
}

// ---------------------------------------------------------------- fp32 -> bf16
__global__ __launch_bounds__(256)
void cvt_bf16(const float* __restrict__ src, unsigned short* __restrict__ dst)
{
    const size_t i = ((size_t)blockIdx.x * 256 + threadIdx.x) * 8;
    const float4 a = *(const float4*)(src + i);
    const float4 b = *(const float4*)(src + i + 4);
    short8 o;
    o[0] = (short)f2bf(a.x); o[1] = (short)f2bf(a.y);
    o[2] = (short)f2bf(a.z); o[3] = (short)f2bf(a.w);
    o[4] = (short)f2bf(b.x); o[5] = (short)f2bf(b.y);
    o[6] = (short)f2bf(b.z); o[7] = (short)f2bf(b.w);
    *(short8*)(dst + i) = o;
}

// ---------------------------------------------------------------- transpose fp32 -> bf16
__global__ __launch_bounds__(256)
void tr_f32_bf16(unsigned short* __restrict__ dst, const float* __restrict__ src,
                 int R, int C)
{
    __shared__ unsigned short T[64][72];
    const int t  = threadIdx.x;
    const int r0 = blockIdx.y * 64, c0 = blockIdx.x * 64;
    const int row = t >> 2, cg = (t & 3) * 16;
    const float* s = src + (size_t)(r0 + row) * C + c0 + cg;
    const float4 f0 = *(const float4*)s;
    const float4 f1 = *(const float4*)(s + 4);
    const float4 f2 = *(const float4*)(s + 8);
    const float4 f3 = *(const float4*)(s + 12);
    T[row][cg + 0]  = f2bf(f0.x); T[row][cg + 1]  = f2bf(f0.y);
    T[row][cg + 2]  = f2bf(f0.z); T[row][cg + 3]  = f2bf(f0.w);
    T[row][cg + 4]  = f2bf(f1.x); T[row][cg + 5]  = f2bf(f1.y);
    T[row][cg + 6]  = f2bf(f1.z); T[row][cg + 7]  = f2bf(f1.w);
    T[row][cg + 8]  = f2bf(f2.x); T[row][cg + 9]  = f2bf(f2.y);
    T[row][cg + 10] = f2bf(f2.z); T[row][cg + 11] = f2bf(f2.w);
    T[row][cg + 12] = f2bf(f3.x); T[row][cg + 13] = f2bf(f3.y);
    T[row][cg + 14] = f2bf(f3.z); T[row][cg + 15] = f2bf(f3.w);
    __syncthreads();
    unsigned short* d = dst + (size_t)(c0 + row) * R + r0 + cg;
    short8 o0, o1;
    #pragma unroll
    for (int k = 0; k < 8; ++k) o0[k] = (short)T[cg + k][row];
    #pragma unroll
    for (int k = 0; k < 8; ++k) o1[k] = (short)T[cg + 8 + k][row];
    *(short8*)d       = o0;
    *(short8*)(d + 8) = o1;
}

// ---------------------------------------------------------------- transpose bf16
__global__ __launch_bounds__(256)
void tr_bf16(unsigned short* __restrict__ dst, const unsigned short* __restrict__ src,
             int R, int C)
{
    __shared__ unsigned short T[64][72];
    const size_t bofs = (size_t)blockIdx.z * (size_t)R * (size_t)C;
    src += bofs; dst += bofs;
    const int t  = threadIdx.x;
    const int r0 = blockIdx.y * 64, c0 = blockIdx.x * 64;
    const int row = t >> 2, cg = (t & 3) * 16;
    const unsigned short* s = src + (size_t)(r0 + row) * C + c0 + cg;
    *(short8*)&T[row][cg]     = *(const short8*)s;
    *(short8*)&T[row][cg + 8] = *(const short8*)(s + 8);
    __syncthreads();
    unsigned short* d = dst + (size_t)(c0 + row) * R + r0 + cg;
    short8 o0, o1;
    #pragma unroll
    for (int k = 0; k < 8; ++k) o0[k] = (short)T[cg + k][row];
    #pragma unroll
    for (int k = 0; k < 8; ++k) o1[k] = (short)T[cg + 8 + k][row];
    *(short8*)d       = o0;
    *(short8*)(d + 8) = o1;
}

// ---------------------------------------------------------------- gather rows (bf16)
__global__ __launch_bounds__(256)
void gather_rows(const unsigned short* __restrict__ xb, const int* __restrict__ sidx,
                 unsigned short* __restrict__ xkg, unsigned short* __restrict__ xvg)
{
    const int blk = blockIdx.x;
    const int b = blk >> 9, j = blk & 511;
    const int t = threadIdx.x;
    int qv = sidx[j];               qv = qv < 0 ? 0 : (qv > LSEQ - 1 ? LSEQ - 1 : qv);
    int cv = qv < SK - 1 ? qv : SK - 1;
    int pv = sidx[cv];              pv = pv < 0 ? 0 : (pv > LSEQ - 1 ? LSEQ - 1 : pv);
    const unsigned int* xs = (const unsigned int*)xb;
    unsigned int* kd = (unsigned int*)xkg;
    unsigned int* vd = (unsigned int*)xvg;
    const size_t dst = ((size_t)b * SK + j) * 256 + t;
    kd[dst] = xs[((size_t)b * LSEQ + pv) * 256 + t];
    vd[dst] = xs[((size_t)b * LSEQ + qv) * 256 + t];
}

// ---------------------------------------------------------------- zero pad rows
__global__ __launch_bounds__(256)
void zero_pad(unsigned short* __restrict__ attpad)
{
    const int i = blockIdx.x * 256 + threadIdx.x;   // 0..4095
    const int b = i >> 9, c = i & 511;
    attpad[(size_t)b * PADROW + c] = 0;
    attpad[(size_t)b * PADROW + (size_t)(LPAD - 1) * 512 + c] = 0;
}

// ---------------------------------------------------------------- GEMM 128x128x32
// MODE 0: bf16 store. MODE 1: conv epilogue (+bias, ELU, MaxPool2 -> bf16).
// MODE 2: +bias, fp32 store.
// Staging: global_load_lds dwordx4 into linear double-buffered LDS, one
// barrier per K-step (m97 structure).
template<int MODE>
__global__ __launch_bounds__(256)
void gemm128(const unsigned short* __restrict__ A, const unsigned short* __restrict__ Bt,
             const float* __restrict__ bias, void* __restrict__ Cout, int K)
{
    __shared__ unsigned short As[2][128 * 32];
    __shared__ unsigned short Bs[2][128 * 32];
    const int t    = threadIdx.x;
    const int n0   = blockIdx.x * 128;
    const int m0   = blockIdx.y * 128;
    const int lane = t & 63, wv = t >> 6;
    const int q = lane >> 4, ln = lane & 15;
    const int wm = (wv & 1) * 64, wn = (wv >> 1) * 64;

    // per-lane global row pointers for the two issues of this wave
    const int srl = (wv << 5) + (lane >> 2);     // rows srl and srl+16
    const int scs = (lane & 3) * 8;              // 16B column (shorts)
    const unsigned short* arow0;
    const unsigned short* arow1;
    if (MODE == 1) {
        const int gr0 = m0 + srl;                // block never straddles a batch
        arow0 = A + (size_t)(gr0 >> 12) * PADROW + (size_t)(gr0 & 4095) * 512 + scs;
        arow1 = arow0 + (size_t)16 * 512;
    } else {
        arow0 = A + (size_t)(m0 + srl) * K + scs;
        arow1 = arow0 + (size_t)16 * K;
    }
    const unsigned short* brow0 = Bt + (size_t)(n0 + srl) * K + scs;
    const unsigned short* brow1 = brow0 + (size_t)16 * K;

    // wave-uniform LDS bases (shorts) for the two 16-row stripes
    const int lb0 = (wv << 5) * 32;
    const int lb1 = lb0 + 16 * 32;

    const f32x4 zero = {0.f, 0.f, 0.f, 0.f};
    f32x4 acc[4][4];
    #pragma unroll
    for (int i = 0; i < 4; ++i)
        #pragma unroll
        for (int j = 0; j < 4; ++j) acc[i][j] = zero;

    // prologue: stage k0 = 0 into buffer 0
    g2l16(arow0, &As[0][lb0]);  g2l16(arow1, &As[0][lb1]);
    g2l16(brow0, &Bs[0][lb0]);  g2l16(brow1, &Bs[0][lb1]);

    for (int k0 = 0; k0 < K; k0 += 32) {
        const int cur = (k0 >> 5) & 1;
        __syncthreads();   // drains vmcnt: buf[cur] staged; prev reads done
        if (k0 + 32 < K) {
            const int nxt = cur ^ 1;
            g2l16(arow0 + k0 + 32, &As[nxt][lb0]);
            g2l16(arow1 + k0 + 32, &As[nxt][lb1]);
            g2l16(brow0 + k0 + 32, &Bs[nxt][lb0]);
            g2l16(brow1 + k0 + 32, &Bs[nxt][lb1]);
        }
        short8 af[4], bf[4];
        #pragma unroll
        for (int mt = 0; mt < 4; ++mt)
            af[mt] = *(const short8*)&As[cur][(wm + mt * 16 + ln) * 32 + q * 8];
        #pragma unroll
        for (int nt = 0; nt < 4; ++nt)
            bf[nt] = *(const short8*)&Bs[cur][(wn + nt * 16 + ln) * 32 + q * 8];
        #pragma unroll
        for (int mt = 0; mt < 4; ++mt)
            #pragma unroll
            for (int nt = 0; nt < 4; ++nt)
                acc[mt][nt] = __builtin_amdgcn_mfma_f32_16x16x32_bf16(af[mt], bf[nt], acc[mt][nt], 0, 0, 0);
    }

    if (MODE == 0) {
        unsigned short* C = (unsigned short*)Cout;
        #pragma unroll
        for (int mt = 0; mt < 4; ++mt)
            #pragma unroll
            for (int r = 0; r < 4; ++r) {
                const int grow = m0 + wm + mt * 16 + q * 4 + r;
                unsigned short* cp = C + (size_t)grow * 512 + n0 + wn + ln;
                #pragma unroll
                for (int nt = 0; nt < 4; ++nt) cp[nt * 16] = f2bf(acc[mt][nt][r]);
            }
    } else if (MODE == 2) {
        float* C = (float*)Cout;
        float bb[4];
        #pragma unroll
        for (int nt = 0; nt < 4; ++nt) bb[nt] = bias[n0 + wn + nt * 16 + ln];
        #pragma unroll
        for (int mt = 0; mt < 4; ++mt)
            #pragma unroll
            for (int r = 0; r < 4; ++r) {
                const int grow = m0 + wm + mt * 16 + q * 4 + r;
                float* cp = C + (size_t)grow * 512 + n0 + wn + ln;
                #pragma unroll
                for (int nt = 0; nt < 4; ++nt) cp[nt * 16] = acc[mt][nt][r] + bb[nt];
            }
    } else { // MODE 1
        unsigned short* C = (unsigned short*)Cout;
        float bb[4];
        #pragma unroll
        for (int nt = 0; nt < 4; ++nt) bb[nt] = bias[n0 + wn + nt * 16 + ln];
        #pragma unroll
        for (int mt = 0; mt < 4; ++mt) {
            const int grow = m0 + wm + mt * 16 + q * 4;
            const int b = grow >> 12, l = grow & 4095;
            unsigned short* cp = C + ((size_t)b * 2048 + (l >> 1)) * 512 + n0 + wn + ln;
            #pragma unroll
            for (int nt = 0; nt < 4; ++nt) {
                float v0 = acc[mt][nt][0] + bb[nt]; v0 = v0 > 0.f ? v0 : __expf(v0) - 1.f;
                float v1 = acc[mt][nt][1] + bb[nt]; v1 = v1 > 0.f ? v1 : __expf(v1) - 1.f;
                float v2 = acc[mt][nt][2] + bb[nt]; v2 = v2 > 0.f ? v2 : __expf(v2) - 1.f;
                float v3 = acc[mt][nt][3] + bb[nt]; v3 = v3 > 0.f ? v3 : __expf(v3) - 1.f;
                cp[nt * 16]       = f2bf(fmaxf(v0, v1));
                cp[512 + nt * 16] = f2bf(fmaxf(v2, v3));
            }
        }
    }
}

// ---------------------------------------------------------------- fused attention v9 (+x0 grid offset)
// grid (8, H, B) x 4 dispatches with x0 in {0,8,16,24} — pure grid partition
// of the original (32, H, B); blocks are independent, numerics identical.
__global__ __launch_bounds__(256, 2)
void attn_fused(const unsigned short* __restrict__ xb, const unsigned short* __restrict__ WqT,
                const unsigned short* __restrict__ Kg, const unsigned short* __restrict__ Vt,
                unsigned short* __restrict__ attpad, int x0)
{
    __shared__ unsigned short Ks[128][72];
    __shared__ unsigned short Vs[64][136];
    __shared__ unsigned short Pp[128][136];   // P per chunk; also Q round-trip
    const int t = threadIdx.x;
    const int wv = t >> 6, lane = t & 63, q = lane >> 4, ln = lane & 15;
    const int l0 = (blockIdx.x + x0) * 128, h = blockIdx.y, b = blockIdx.z;
    const int qr0 = wv * 32;
    const f32x4 zero = {0.f, 0.f, 0.f, 0.f};

    // staging maps
    const unsigned short* kgb = Kg + (size_t)b * SK * 512 + h * 64;        // + s*512 + e
    const unsigned short* vtb = Vt + ((size_t)(b * EDIM + h * 64)) * SK;   // + d*SK + s
    const int ksr = t >> 1, ksc = (t & 1) * 32;    // K: row s, 32-short half
    const int vsr = t >> 2, vsc = (t & 3) * 32;    // V: row d, 32-short quarter

    // prefetch chunk 0 (flies during Q projection)
    short8 kp0, kp1, kp2, kp3, vp0, vp1, vp2, vp3;
    {
        const unsigned short* ks = kgb + (size_t)ksr * 512 + ksc;
        kp0 = *(const short8*)ks;        kp1 = *(const short8*)(ks + 8);
        kp2 = *(const short8*)(ks + 16); kp3 = *(const short8*)(ks + 24);
        const unsigned short* vs = vtb + (size_t)vsr * SK + vsc;
        vp0 = *(const short8*)vs;        vp1 = *(const short8*)(vs + 8);
        vp2 = *(const short8*)(vs + 16); vp3 = *(const short8*)(vs + 24);
    }

    // --- Q projection: rows qr0 + g*16 + ln (g=0,1), 64 head cols, k=512
    f32x4 qacc[2][4];
    #pragma unroll
    for (int g = 0; g < 2; ++g)
        #pragma unroll
        for (int nt = 0; nt < 4; ++nt) qacc[g][nt] = zero;
    const unsigned short* xr0 = xb + ((size_t)(b * LSEQ + l0 + qr0 + ln)) * 512 + q * 8;
    const unsigned short* xr1 = xr0 + (size_t)16 * 512;
    const unsigned short* wqp = WqT + ((size_t)(h * 64 + ln)) * 512 + q * 8;
    for (int ks = 0; ks < 16; ++ks) {
        const short8 ax0 = *(const short8*)(xr0 + ks * 32);
        const short8 ax1 = *(const short8*)(xr1 + ks * 32);
        #pragma unroll
        for (int nt = 0; nt < 4; ++nt) {
            const short8 bw = *(const short8*)(wqp + nt * 16 * 512 + ks * 32);
            qacc[0][nt] = __builtin_amdgcn_mfma_f32_16x16x32_bf16(ax0, bw, qacc[0][nt], 0, 0, 0);
            qacc[1][nt] = __builtin_amdgcn_mfma_f32_16x16x32_bf16(ax1, bw, qacc[1][nt], 0, 0, 0);
        }
    }
    #pragma unroll
    for (int g = 0; g < 2; ++g)
        #pragma unroll
        for (int nt = 0; nt < 4; ++nt)
            #pragma unroll
            for (int r = 0; r < 4; ++r)
                Pp[qr0 + g * 16 + q * 4 + r][nt * 16 + ln] = f2bf(qacc[g][nt][r]);
    asm volatile("s_waitcnt lgkmcnt(0)" ::: "memory");   // wave-private round trip
    short8 bq[2][2];
    #pragma unroll
    for (int g = 0; g < 2; ++g) {
        bq[g][0] = *(const short8*)&Pp[qr0 + g * 16 + ln][q * 8];
        bq[g][1] = *(const short8*)&Pp[qr0 + g * 16 + ln][q * 8 + 32];
    }

    // --- flash state in base-2 domain (per q-col = ln, per group g)
    float m_run[2] = {-1e30f, -1e30f}, l_run[2] = {0.f, 0.f};
    f32x4 o[2][4];
    #pragma unroll
    for (int g = 0; g < 2; ++g)
        #pragma unroll
        for (int j = 0; j < 4; ++j) o[g][j] = zero;

    for (int c = 0; c < 4; ++c) {
        // store staged chunk (regs were prefetched)
        *(short8*)&Ks[ksr][ksc]      = kp0;  *(short8*)&Ks[ksr][ksc + 8]  = kp1;
        *(short8*)&Ks[ksr][ksc + 16] = kp2;  *(short8*)&Ks[ksr][ksc + 24] = kp3;
        *(short8*)&Vs[vsr][vsc]      = vp0;  *(short8*)&Vs[vsr][vsc + 8]  = vp1;
        *(short8*)&Vs[vsr][vsc + 16] = vp2;  *(short8*)&Vs[vsr][vsc + 24] = vp3;
        __syncthreads();   // A: Ks/Vs ready

        // scores (transposed, pre-scaled by 0.125*log2e):
        // St[s = mt*16+quad*4+r][qcol = g*16+ln]
        f32x4 st[8][2];
        #pragma unroll
        for (int mt = 0; mt < 8; ++mt) {
            const short8 ak0 = *(const short8*)&Ks[mt * 16 + ln][q * 8];
            const short8 ak1 = *(const short8*)&Ks[mt * 16 + ln][q * 8 + 32];
            #pragma unroll
            for (int g = 0; g < 2; ++g) {
                f32x4 a = zero;
                a = __builtin_amdgcn_mfma_f32_16x16x32_bf16(ak0, bq[g][0], a, 0, 0, 0);
                a = __builtin_amdgcn_mfma_f32_16x16x32_bf16(ak1, bq[g][1], a, 0, 0, 0);
                #pragma unroll
                for (int r = 0; r < 4; ++r) a[r] *= SCALE2;
                st[mt][g] = a;
            }
        }

        // online softmax (base-2): max, alpha, exp2 + cvt_pk pack, l fold
        float alpha_[2];
        #pragma unroll
        for (int g = 0; g < 2; ++g) {
            float mx = st[0][g][0];
            #pragma unroll
            for (int mt = 0; mt < 8; ++mt)
                #pragma unroll
                for (int r = 0; r < 4; ++r) mx = fmaxf(mx, st[mt][g][r]);
            mx = fmaxf(mx, __shfl_xor(mx, 16));
            mx = fmaxf(mx, __shfl_xor(mx, 32));
            const float m_new = fmaxf(m_run[g], mx);
            alpha_[g] = __builtin_amdgcn_exp2f(m_run[g] - m_new);
            m_run[g] = m_new;
            float ls = 0.f;
            #pragma unroll
            for (int mt = 0; mt < 8; ++mt) {
                const float p0 = __builtin_amdgcn_exp2f(st[mt][g][0] - m_new);
                const float p1 = __builtin_amdgcn_exp2f(st[mt][g][1] - m_new);
                const float p2 = __builtin_amdgcn_exp2f(st[mt][g][2] - m_new);
                const float p3 = __builtin_amdgcn_exp2f(st[mt][g][3] - m_new);
                ls += (p0 + p1) + (p2 + p3);
                uint2 pw;
                pw.x = cvt_pk_bf16(p0, p1);
                pw.y = cvt_pk_bf16(p2, p3);
                *(uint2*)&Pp[qr0 + g * 16 + ln][mt * 16 + q * 4] = pw;
            }
            ls += __shfl_xor(ls, 16);
            ls += __shfl_xor(ls, 32);
            l_run[g] = l_run[g] * alpha_[g] + ls;
        }

        // rescale O (rows q' = quad*4+r of tile g)
        #pragma unroll
        for (int g = 0; g < 2; ++g) {
            #pragma unroll
            for (int r = 0; r < 4; ++r) {
                const float ab = __shfl(alpha_[g], q * 4 + r);
                #pragma unroll
                for (int j = 0; j < 4; ++j) o[g][j][r] *= ab;
            }
        }

        // prefetch next chunk into regs (overlaps PV)
        if (c < 3) {
            const unsigned short* ks = kgb + (size_t)((c + 1) * 128 + ksr) * 512 + ksc;
            kp0 = *(const short8*)ks;        kp1 = *(const short8*)(ks + 8);
            kp2 = *(const short8*)(ks + 16); kp3 = *(const short8*)(ks + 24);
            const unsigned short* vs = vtb + (size_t)vsr * SK + (c + 1) * 128 + vsc;
            vp0 = *(const short8*)vs;        vp1 = *(const short8*)(vs + 8);
            vp2 = *(const short8*)(vs + 16); vp3 = *(const short8*)(vs + 24);
        }

        asm volatile("s_waitcnt lgkmcnt(0)" ::: "memory");   // P visible to wave

        // PV: A = P rows (q), B = Vs rows (d), k = 128 chunk
        #pragma unroll
        for (int ks2 = 0; ks2 < 4; ++ks2) {
            const short8 ap0 = *(const short8*)&Pp[qr0 + ln][ks2 * 32 + q * 8];
            const short8 ap1 = *(const short8*)&Pp[qr0 + 16 + ln][ks2 * 32 + q * 8];
            #pragma unroll
            for (int j = 0; j < 4; ++j) {
                const short8 bv = *(const short8*)&Vs[j * 16 + ln][ks2 * 32 + q * 8];
                o[0][j] = __builtin_amdgcn_mfma_f32_16x16x32_bf16(ap0, bv, o[0][j], 0, 0, 0);
                o[1][j] = __builtin_amdgcn_mfma_f32_16x16x32_bf16(ap1, bv, o[1][j], 0, 0, 0);
            }
        }
        __syncthreads();   // B: Ks/Vs reads done before restage
    }

    // epilogue: scale by 1/l, store rows l0+qr0+g*16+q*4+r (+1 pad offset)
    #pragma unroll
    for (int g = 0; g < 2; ++g) {
        const float li = 1.f / l_run[g];
        #pragma unroll
        for (int r = 0; r < 4; ++r) {
            const float ib = __shfl(li, q * 4 + r);
            const int rl = qr0 + g * 16 + q * 4 + r;
            #pragma unroll
            for (int j = 0; j < 4; ++j)
                attpad[((size_t)b * PADROW) + (size_t)(l0 + rl + 1) * 512 + h * 64 + j * 16 + ln]
                    = f2bf(o[g][j][r] * ib);
        }
    }
}

// ---------------------------------------------------------------- launcher
extern "C" void kernel_launch(void* const* d_in, const int* in_sizes, int n_in,
                              void* d_out, int out_size, void* d_ws, size_t ws_size,
                              hipStream_t stream)
{
    const float* x    = (const float*)d_in[0];
    const float* Wq   = (const float*)d_in[1];
    const float* Wk   = (const float*)d_in[2];
    const float* Wv   = (const float*)d_in[3];
    const float* cw   = (const float*)d_in[4];   // [1536][512] flat fp32
    const float* cb   = (const float*)d_in[5];
    const float* mw   = (const float*)d_in[6];
    const float* mb2  = (const float*)d_in[7];
    const int*   sidx = (const int*)d_in[8];
    float* out = (float*)d_out;

    char* ws = (char*)d_ws;
    unsigned short* xb    = (unsigned short*)(ws + 0);           // 33,554,432 B
    unsigned short* Pool  = (unsigned short*)(ws + 0);           // alias (xb dead post-attn)
    unsigned short* Pad   = (unsigned short*)(ws + 33554432);    // 33,570,816 B
    unsigned short* xkg   = (unsigned short*)(ws + 33554432);    // alias Pad head
    unsigned short* xvg   = (unsigned short*)(ws + 37748736);    // alias
    unsigned short* Vg    = (unsigned short*)(ws + 41943040);    // alias
    unsigned short* Kg    = (unsigned short*)(ws + 67125248);    //  4,194,304 B
    unsigned short* Vt    = (unsigned short*)(ws + 71319552);    //  4,194,304 B
    unsigned short* WqT   = (unsigned short*)(ws + 75513856);    //    524,288 B
    unsigned short* WkT   = (unsigned short*)(ws + 76038144);
    unsigned short* WvT   = (unsigned short*)(ws + 76562432);
    unsigned short* CombT = (unsigned short*)(ws + 77086720);
    unsigned short* ConvT = (unsigned short*)(ws + 77611008);    // 1,572,864 B -> end 79,183,872

    dim3 blk(256);

    // 0. x -> bf16
    cvt_bf16<<<dim3(8192), blk, 0, stream>>>(x, xb);

    // 1. weight transposes (fp32 -> bf16): dst[N][K] = W[K][N]
    tr_f32_bf16<<<dim3(8, 8),  blk, 0, stream>>>(WqT,   Wq, 512, 512);
    tr_f32_bf16<<<dim3(8, 8),  blk, 0, stream>>>(WkT,   Wk, 512, 512);
    tr_f32_bf16<<<dim3(8, 8),  blk, 0, stream>>>(WvT,   Wv, 512, 512);
    tr_f32_bf16<<<dim3(8, 8),  blk, 0, stream>>>(CombT, mw, 512, 512);
    tr_f32_bf16<<<dim3(8, 24), blk, 0, stream>>>(ConvT, cw, 1536, 512);

    // 2. gathers (xkg/xvg in Pad head; consumed before zero_pad/attn)
    gather_rows<<<dim3(4096), blk, 0, stream>>>(xb, sidx, xkg, xvg);

    // 3. K/V projections (per-batch 512 gathered rows)
    gemm128<0><<<dim3(4, 32), blk, 0, stream>>>(xkg, WkT, nullptr, Kg, 512);
    gemm128<0><<<dim3(4, 32), blk, 0, stream>>>(xvg, WvT, nullptr, Vg, 512);

    // 4. Vt[b][e][s] = Vg[b][s][e]
    tr_bf16<<<dim3(8, 8, 8), blk, 0, stream>>>(Vt, Vg, 512, 512);

    // 5. attention — FOUR grid-partition dispatches (measurement probe:
    //    frees the top-5-by-duration slots so conv/dense/cvt surface)
    zero_pad<<<dim3(16), blk, 0, stream>>>(Pad);
    attn_fused<<<dim3(8, 8, 8), blk, 0, stream>>>(xb, WqT, Kg, Vt, Pad, 0);
    attn_fused<<<dim3(8, 8, 8), blk, 0, stream>>>(xb, WqT, Kg, Vt, Pad, 8);
    attn_fused<<<dim3(8, 8, 8), blk, 0, stream>>>(xb, WqT, Kg, Vt, Pad, 16);
    attn_fused<<<dim3(8, 8, 8), blk, 0, stream>>>(xb, WqT, Kg, Vt, Pad, 24);

    // 6. conv (K=1536) + bias + ELU + pool -> Pool (aliases dead xb)
    gemm128<1><<<dim3(4, 256), blk, 0, stream>>>(Pad, ConvT, cb, Pool, 1536);

    // 7. final dense + bias -> out (fp32)
    gemm128<2><<<dim3(4, 128), blk, 0, stream>>>(Pool, CombT, mb2, out, 512);
}

// Round 11
// 398.143 us; speedup vs baseline: 1.0425x; 1.0425x over previous
//
#include <hip/hip_runtime.h>

// ProbAttention on MI355X (gfx950). Inputs/outputs fp32; compute in bf16 MFMA
// (mfma_f32_16x16x32_bf16, fp32 accumulate). B=8, L=4096, D=512, H=8, DK=64,
// S=512, CONV_K=3, POOL=2.
//
// v12: attn reverted to single (32,8,8) dispatch (the v11 4-way split was a
// measurement probe; it cost +33us of lost inter-dispatch overlap and is no
// longer needed). Probe finding: conv gemm128<1> = 94.5us, 545 TF, MfmaUtil
// 21% (= its pure-MFMA floor of 20.6us), FETCH 187MB @ 2.2TB/s — latency/
// structure-bound, not BW-bound. v12 replaces the conv GEMM with gemm256n:
//  - BN=256 tile (BM=128, BK=32): 32 MFMA per barrier per wave (2x), A's
//    N-block re-read factor halves (4 -> 2). Same one-barrier-per-K-step
//    global_load_lds protocol (verified in v10), same K accumulation order
//    per output element -> bit-identical numerics.
//  - XCD-colocating block map: c=bid&7 owns M-chunk [c*32,c*32+32) with the
//    two N-halves of each M-panel temporally adjacent (bids 16j+c, 16j+8+c)
//    so the shared A-panel's 2nd read is an L2 hit (T1 mechanism; bijective,
//    512 blocks % 8 == 0).
// Proj/dense keep gemm128 (proj grid is already thin at 128 blocks).

typedef __attribute__((ext_vector_type(8))) short  short8;
typedef __attribute__((ext_vector_type(4))) short  short4b;
typedef __attribute__((ext_vector_type(4))) float  f32x4;

#define LSEQ   4096
#define SK     512
#define EDIM   512
#define LPAD   4098            // L + 2
#define PADROW 2098176         // LPAD * 512 (shorts)
#define SCALE2 0.180336880f    // 0.125 * log2(e) — fp32 score scale for exp2

static __device__ __forceinline__ float bf2f(unsigned short h) {
    union { unsigned int u; float f; } v; v.u = ((unsigned int)h) << 16; return v.f;
}
static __device__ __forceinline__ unsigned short f2bf(float f) {
    union { float f; unsigned int u; } v; v.f = f;
    unsigned int r = (v.u + 0x7fffu + ((v.u >> 16) & 1u)) >> 16;
    return (unsigned short)r;
}
static __device__ __forceinline__ unsigned int cvt_pk_bf16(float lo, float hi) {
    unsigned int r;
    asm("v_cvt_pk_bf16_f32 %0, %1, %2" : "=v"(r) : "v"(lo), "v"(hi));
    return r;   // dst[15:0] = bf16(lo), dst[31:16] = bf16(hi)
}
// async global -> LDS, 16 B per lane; LDS dest = wave-uniform base + lane*16
typedef __attribute__((address_space(1))) const unsigned int  gu32;
typedef __attribute__((address_space(3))) unsigned int        lu32;
static __device__ __forceinline__ void g2l16(const unsigned short* g, unsigned short* l)
{
    __builtin_amdgcn_global_load_lds((gu32*)g, (lu32*)l, 16, 0, 0);
}

// ---------------------------------------------------------------- fp32 -> bf16
__global__ __launch_bounds__(256)
void cvt_bf16(const float* __restrict__ src, unsigned short* __restrict__ dst)
{
    const size_t i = ((size_t)blockIdx.x * 256 + threadIdx.x) * 8;
    const float4 a = *(const float4*)(src + i);
    const float4 b = *(const float4*)(src + i + 4);
    short8 o;
    o[0] = (short)f2bf(a.x); o[1] = (short)f2bf(a.y);
    o[2] = (short)f2bf(a.z); o[3] = (short)f2bf(a.w);
    o[4] = (short)f2bf(b.x); o[5] = (short)f2bf(b.y);
    o[6] = (short)f2bf(b.z); o[7] = (short)f2bf(b.w);
    *(short8*)(dst + i) = o;
}

// ---------------------------------------------------------------- transpose fp32 -> bf16
__global__ __launch_bounds__(256)
void tr_f32_bf16(unsigned short* __restrict__ dst, const float* __restrict__ src,
                 int R, int C)
{
    __shared__ unsigned short T[64][72];
    const int t  = threadIdx.x;
    const int r0 = blockIdx.y * 64, c0 = blockIdx.x * 64;
    const int row = t >> 2, cg = (t & 3) * 16;
    const float* s = src + (size_t)(r0 + row) * C + c0 + cg;
    const float4 f0 = *(const float4*)s;
    const float4 f1 = *(const float4*)(s + 4);
    const float4 f2 = *(const float4*)(s + 8);
    const float4 f3 = *(const float4*)(s + 12);
    T[row][cg + 0]  = f2bf(f0.x); T[row][cg + 1]  = f2bf(f0.y);
    T[row][cg + 2]  = f2bf(f0.z); T[row][cg + 3]  = f2bf(f0.w);
    T[row][cg + 4]  = f2bf(f1.x); T[row][cg + 5]  = f2bf(f1.y);
    T[row][cg + 6]  = f2bf(f1.z); T[row][cg + 7]  = f2bf(f1.w);
    T[row][cg + 8]  = f2bf(f2.x); T[row][cg + 9]  = f2bf(f2.y);
    T[row][cg + 10] = f2bf(f2.z); T[row][cg + 11] = f2bf(f2.w);
    T[row][cg + 12] = f2bf(f3.x); T[row][cg + 13] = f2bf(f3.y);
    T[row][cg + 14] = f2bf(f3.z); T[row][cg + 15] = f2bf(f3.w);
    __syncthreads();
    unsigned short* d = dst + (size_t)(c0 + row) * R + r0 + cg;
    short8 o0, o1;
    #pragma unroll
    for (int k = 0; k < 8; ++k) o0[k] = (short)T[cg + k][row];
    #pragma unroll
    for (int k = 0; k < 8; ++k) o1[k] = (short)T[cg + 8 + k][row];
    *(short8*)d       = o0;
    *(short8*)(d + 8) = o1;
}

// ---------------------------------------------------------------- transpose bf16
__global__ __launch_bounds__(256)
void tr_bf16(unsigned short* __restrict__ dst, const unsigned short* __restrict__ src,
             int R, int C)
{
    __shared__ unsigned short T[64][72];
    const size_t bofs = (size_t)blockIdx.z * (size_t)R * (size_t)C;
    src += bofs; dst += bofs;
    const int t  = threadIdx.x;
    const int r0 = blockIdx.y * 64, c0 = blockIdx.x * 64;
    const int row = t >> 2, cg = (t & 3) * 16;
    const unsigned short* s = src + (size_t)(r0 + row) * C + c0 + cg;
    *(short8*)&T[row][cg]     = *(const short8*)s;
    *(short8*)&T[row][cg + 8] = *(const short8*)(s + 8);
    __syncthreads();
    unsigned short* d = dst + (size_t)(c0 + row) * R + r0 + cg;
    short8 o0, o1;
    #pragma unroll
    for (int k = 0; k < 8; ++k) o0[k] = (short)T[cg + k][row];
    #pragma unroll
    for (int k = 0; k < 8; ++k) o1[k] = (short)T[cg + 8 + k][row];
    *(short8*)d       = o0;
    *(short8*)(d + 8) = o1;
}

// ---------------------------------------------------------------- gather rows (bf16)
__global__ __launch_bounds__(256)
void gather_rows(const unsigned short* __restrict__ xb, const int* __restrict__ sidx,
                 unsigned short* __restrict__ xkg, unsigned short* __restrict__ xvg)
{
    const int blk = blockIdx.x;
    const int b = blk >> 9, j = blk & 511;
    const int t = threadIdx.x;
    int qv = sidx[j];               qv = qv < 0 ? 0 : (qv > LSEQ - 1 ? LSEQ - 1 : qv);
    int cv = qv < SK - 1 ? qv : SK - 1;
    int pv = sidx[cv];              pv = pv < 0 ? 0 : (pv > LSEQ - 1 ? LSEQ - 1 : pv);
    const unsigned int* xs = (const unsigned int*)xb;
    unsigned int* kd = (unsigned int*)xkg;
    unsigned int* vd = (unsigned int*)xvg;
    const size_t dst = ((size_t)b * SK + j) * 256 + t;
    kd[dst] = xs[((size_t)b * LSEQ + pv) * 256 + t];
    vd[dst] = xs[((size_t)b * LSEQ + qv) * 256 + t];
}

// ---------------------------------------------------------------- zero pad rows
__global__ __launch_bounds__(256)
void zero_pad(unsigned short* __restrict__ attpad)
{
    const int i = blockIdx.x * 256 + threadIdx.x;   // 0..4095
    const int b = i >> 9, c = i & 511;
    attpad[(size_t)b * PADROW + c] = 0;
    attpad[(size_t)b * PADROW + (size_t)(LPAD - 1) * 512 + c] = 0;
}

// ---------------------------------------------------------------- GEMM 128x128x32
// MODE 0: bf16 store. MODE 2: +bias, fp32 store. (conv now uses gemm256n)
template<int MODE>
__global__ __launch_bounds__(256)
void gemm128(const unsigned short* __restrict__ A, const unsigned short* __restrict__ Bt,
             const float* __restrict__ bias, void* __restrict__ Cout, int K)
{
    __shared__ unsigned short As[2][128 * 32];
    __shared__ unsigned short Bs[2][128 * 32];
    const int t    = threadIdx.x;
    const int n0   = blockIdx.x * 128;
    const int m0   = blockIdx.y * 128;
    const int lane = t & 63, wv = t >> 6;
    const int q = lane >> 4, ln = lane & 15;
    const int wm = (wv & 1) * 64, wn = (wv >> 1) * 64;

    const int srl = (wv << 5) + (lane >> 2);     // rows srl and srl+16
    const int scs = (lane & 3) * 8;              // 16B column (shorts)
    const unsigned short* arow0 = A + (size_t)(m0 + srl) * K + scs;
    const unsigned short* arow1 = arow0 + (size_t)16 * K;
    const unsigned short* brow0 = Bt + (size_t)(n0 + srl) * K + scs;
    const unsigned short* brow1 = brow0 + (size_t)16 * K;

    const int lb0 = (wv << 5) * 32;
    const int lb1 = lb0 + 16 * 32;

    const f32x4 zero = {0.f, 0.f, 0.f, 0.f};
    f32x4 acc[4][4];
    #pragma unroll
    for (int i = 0; i < 4; ++i)
        #pragma unroll
        for (int j = 0; j < 4; ++j) acc[i][j] = zero;

    g2l16(arow0, &As[0][lb0]);  g2l16(arow1, &As[0][lb1]);
    g2l16(brow0, &Bs[0][lb0]);  g2l16(brow1, &Bs[0][lb1]);

    for (int k0 = 0; k0 < K; k0 += 32) {
        const int cur = (k0 >> 5) & 1;
        __syncthreads();   // drains vmcnt: buf[cur] staged; prev reads done
        if (k0 + 32 < K) {
            const int nxt = cur ^ 1;
            g2l16(arow0 + k0 + 32, &As[nxt][lb0]);
            g2l16(arow1 + k0 + 32, &As[nxt][lb1]);
            g2l16(brow0 + k0 + 32, &Bs[nxt][lb0]);
            g2l16(brow1 + k0 + 32, &Bs[nxt][lb1]);
        }
        short8 af[4], bf[4];
        #pragma unroll
        for (int mt = 0; mt < 4; ++mt)
            af[mt] = *(const short8*)&As[cur][(wm + mt * 16 + ln) * 32 + q * 8];
        #pragma unroll
        for (int nt = 0; nt < 4; ++nt)
            bf[nt] = *(const short8*)&Bs[cur][(wn + nt * 16 + ln) * 32 + q * 8];
        #pragma unroll
        for (int mt = 0; mt < 4; ++mt)
            #pragma unroll
            for (int nt = 0; nt < 4; ++nt)
                acc[mt][nt] = __builtin_amdgcn_mfma_f32_16x16x32_bf16(af[mt], bf[nt], acc[mt][nt], 0, 0, 0);
    }

    if (MODE == 0) {
        unsigned short* C = (unsigned short*)Cout;
        #pragma unroll
        for (int mt = 0; mt < 4; ++mt)
            #pragma unroll
            for (int r = 0; r < 4; ++r) {
                const int grow = m0 + wm + mt * 16 + q * 4 + r;
                unsigned short* cp = C + (size_t)grow * 512 + n0 + wn + ln;
                #pragma unroll
                for (int nt = 0; nt < 4; ++nt) cp[nt * 16] = f2bf(acc[mt][nt][r]);
            }
    } else { // MODE 2
        float* C = (float*)Cout;
        float bb[4];
        #pragma unroll
        for (int nt = 0; nt < 4; ++nt) bb[nt] = bias[n0 + wn + nt * 16 + ln];
        #pragma unroll
        for (int mt = 0; mt < 4; ++mt)
            #pragma unroll
            for (int r = 0; r < 4; ++r) {
                const int grow = m0 + wm + mt * 16 + q * 4 + r;
                float* cp = C + (size_t)grow * 512 + n0 + wn + ln;
                #pragma unroll
                for (int nt = 0; nt < 4; ++nt) cp[nt * 16] = acc[mt][nt][r] + bb[nt];
            }
    }
}

// ---------------------------------------------------------------- conv GEMM 128x256x32
// M=32768 (Pad rows, im2col via 1536 consecutive shorts spanning 3 padded
// rows), N=512 in 2 blocks of 256, K=1536. One barrier per K-step, same
// g2l16 protocol as gemm128. 4 waves: wave wv -> wm=(wv&1)*64, wn=(wv>>1)*128;
// per wave 64x128 output, acc[4][8], 32 MFMA/K-step (2x gemm128).
// LDS = 2*(128+256)*32*2 = 49,152 B. Grid 512 blocks, 1-D with an
// XCD-colocating map: c=bid&7 owns M-chunk [c*32,c*32+32); the two N-halves
// of M-panel j are bids 16j+c and 16j+8+c (temporally adjacent, same XCD
// under round-robin dispatch) so the 2nd A-panel read hits L2.
// Epilogue: +bias, ELU, MaxPool2 -> bf16 (identical ops to old MODE 1).
__global__ __launch_bounds__(256)
void gemm256n(const unsigned short* __restrict__ A, const unsigned short* __restrict__ Bt,
              const float* __restrict__ bias, unsigned short* __restrict__ Cout, int K)
{
    __shared__ unsigned short As[2][128 * 32];
    __shared__ unsigned short Bs[2][256 * 32];
    const int t    = threadIdx.x;
    const int bid  = blockIdx.x;
    const int mi   = (bid & 7) * 32 + ((bid >> 3) >> 1);
    const int ni   = (bid >> 3) & 1;
    const int m0   = mi * 128;
    const int n0   = ni * 256;
    const int lane = t & 63, wv = t >> 6;
    const int q = lane >> 4, ln = lane & 15;
    const int wm = (wv & 1) * 64, wn = (wv >> 1) * 128;

    // A staging: rows m0 + srl, srl+16 (covers 0..127 across 4 waves)
    const int srl = (wv << 5) + (lane >> 2);
    const int scs = (lane & 3) * 8;
    const int gr0 = m0 + srl;                    // block never straddles a batch
    const unsigned short* arow0 = A + (size_t)(gr0 >> 12) * PADROW + (size_t)(gr0 & 4095) * 512 + scs;
    const unsigned short* arow1 = arow0 + (size_t)16 * 512;
    // B staging: rows n0 + brl + {0,16,32,48} (covers 0..255 across 4 waves)
    const int brl = (wv << 6) + (lane >> 2);
    const unsigned short* brow0 = Bt + (size_t)(n0 + brl) * K + scs;
    const unsigned short* brow1 = brow0 + (size_t)16 * K;
    const unsigned short* brow2 = brow0 + (size_t)32 * K;
    const unsigned short* brow3 = brow0 + (size_t)48 * K;

    // wave-uniform LDS stripe bases (shorts)
    const int alb0 = (wv << 5) * 32, alb1 = alb0 + 16 * 32;
    const int blb0 = (wv << 6) * 32;
    const int blb1 = blb0 + 16 * 32, blb2 = blb0 + 32 * 32, blb3 = blb0 + 48 * 32;

    const f32x4 zero = {0.f, 0.f, 0.f, 0.f};
    f32x4 acc[4][8];
    #pragma unroll
    for (int i = 0; i < 4; ++i)
        #pragma unroll
        for (int j = 0; j < 8; ++j) acc[i][j] = zero;

    // prologue: stage k0 = 0 into buffer 0
    g2l16(arow0, &As[0][alb0]);  g2l16(arow1, &As[0][alb1]);
    g2l16(brow0, &Bs[0][blb0]);  g2l16(brow1, &Bs[0][blb1]);
    g2l16(brow2, &Bs[0][blb2]);  g2l16(brow3, &Bs[0][blb3]);

    for (int k0 = 0; k0 < K; k0 += 32) {
        const int cur = (k0 >> 5) & 1;
        __syncthreads();   // drains vmcnt: buf[cur] staged; prev reads done
        if (k0 + 32 < K) {
            const int nxt = cur ^ 1;
            g2l16(arow0 + k0 + 32, &As[nxt][alb0]);
            g2l16(arow1 + k0 + 32, &As[nxt][alb1]);
            g2l16(brow0 + k0 + 32, &Bs[nxt][blb0]);
            g2l16(brow1 + k0 + 32, &Bs[nxt][blb1]);
            g2l16(brow2 + k0 + 32, &Bs[nxt][blb2]);
            g2l16(brow3 + k0 + 32, &Bs[nxt][blb3]);
        }
        short8 af[4], bf[8];
        #pragma unroll
        for (int mt = 0; mt < 4; ++mt)
            af[mt] = *(const short8*)&As[cur][(wm + mt * 16 + ln) * 32 + q * 8];
        #pragma unroll
        for (int nt = 0; nt < 8; ++nt)
            bf[nt] = *(const short8*)&Bs[cur][(wn + nt * 16 + ln) * 32 + q * 8];
        #pragma unroll
        for (int mt = 0; mt < 4; ++mt)
            #pragma unroll
            for (int nt = 0; nt < 8; ++nt)
                acc[mt][nt] = __builtin_amdgcn_mfma_f32_16x16x32_bf16(af[mt], bf[nt], acc[mt][nt], 0, 0, 0);
    }

    // epilogue: +bias, ELU, MaxPool2 -> bf16 (same ops/order as old MODE 1)
    float bb[8];
    #pragma unroll
    for (int nt = 0; nt < 8; ++nt) bb[nt] = bias[n0 + wn + nt * 16 + ln];
    #pragma unroll
    for (int mt = 0; mt < 4; ++mt) {
        const int grow = m0 + wm + mt * 16 + q * 4;
        const int b = grow >> 12, l = grow & 4095;
        unsigned short* cp = Cout + ((size_t)b * 2048 + (l >> 1)) * 512 + n0 + wn + ln;
        #pragma unroll
        for (int nt = 0; nt < 8; ++nt) {
            float v0 = acc[mt][nt][0] + bb[nt]; v0 = v0 > 0.f ? v0 : __expf(v0) - 1.f;
            float v1 = acc[mt][nt][1] + bb[nt]; v1 = v1 > 0.f ? v1 : __expf(v1) - 1.f;
            float v2 = acc[mt][nt][2] + bb[nt]; v2 = v2 > 0.f ? v2 : __expf(v2) - 1.f;
            float v3 = acc[mt][nt][3] + bb[nt]; v3 = v3 > 0.f ? v3 : __expf(v3) - 1.f;
            cp[nt * 16]       = f2bf(fmaxf(v0, v1));
            cp[512 + nt * 16] = f2bf(fmaxf(v2, v3));
        }
    }
}

// ---------------------------------------------------------------- fused attention v9
// grid (L/128, H, B), 256 threads = 4 waves; wave w owns 32 q-rows (2 tiles).
// S in 4 chunks of 128, online softmax in base-2 domain; P packed with
// v_cvt_pk_bf16_f32. K chunk (128x64) and V chunk (64x128) in LDS shared by
// all 4 waves; next chunk register-prefetched during softmax/PV; full-width
// Pp round-trip, ONE lgkmcnt drain + one PV sweep per chunk.
// LDS = 18,432 + 17,408 + 34,816 = 70,656 B (2 blocks/CU).
__global__ __launch_bounds__(256, 2)
void attn_fused(const unsigned short* __restrict__ xb, const unsigned short* __restrict__ WqT,
                const unsigned short* __restrict__ Kg, const unsigned short* __restrict__ Vt,
                unsigned short* __restrict__ attpad)
{
    __shared__ unsigned short Ks[128][72];
    __shared__ unsigned short Vs[64][136];
    __shared__ unsigned short Pp[128][136];   // P per chunk; also Q round-trip
    const int t = threadIdx.x;
    const int wv = t >> 6, lane = t & 63, q = lane >> 4, ln = lane & 15;
    const int l0 = blockIdx.x * 128, h = blockIdx.y, b = blockIdx.z;
    const int qr0 = wv * 32;
    const f32x4 zero = {0.f, 0.f, 0.f, 0.f};

    // staging maps
    const unsigned short* kgb = Kg + (size_t)b * SK * 512 + h * 64;        // + s*512 + e
    const unsigned short* vtb = Vt + ((size_t)(b * EDIM + h * 64)) * SK;   // + d*SK + s
    const int ksr = t >> 1, ksc = (t & 1) * 32;    // K: row s, 32-short half
    const int vsr = t >> 2, vsc = (t & 3) * 32;    // V: row d, 32-short quarter

    // prefetch chunk 0 (flies during Q projection)
    short8 kp0, kp1, kp2, kp3, vp0, vp1, vp2, vp3;
    {
        const unsigned short* ks = kgb + (size_t)ksr * 512 + ksc;
        kp0 = *(const short8*)ks;        kp1 = *(const short8*)(ks + 8);
        kp2 = *(const short8*)(ks + 16); kp3 = *(const short8*)(ks + 24);
        const unsigned short* vs = vtb + (size_t)vsr * SK + vsc;
        vp0 = *(const short8*)vs;        vp1 = *(const short8*)(vs + 8);
        vp2 = *(const short8*)(vs + 16); vp3 = *(const short8*)(vs + 24);
    }

    // --- Q projection: rows qr0 + g*16 + ln (g=0,1), 64 head cols, k=512
    f32x4 qacc[2][4];
    #pragma unroll
    for (int g = 0; g < 2; ++g)
        #pragma unroll
        for (int nt = 0; nt < 4; ++nt) qacc[g][nt] = zero;
    const unsigned short* xr0 = xb + ((size_t)(b * LSEQ + l0 + qr0 + ln)) * 512 + q * 8;
    const unsigned short* xr1 = xr0 + (size_t)16 * 512;
    const unsigned short* wqp = WqT + ((size_t)(h * 64 + ln)) * 512 + q * 8;
    for (int ks = 0; ks < 16; ++ks) {
        const short8 ax0 = *(const short8*)(xr0 + ks * 32);
        const short8 ax1 = *(const short8*)(xr1 + ks * 32);
        #pragma unroll
        for (int nt = 0; nt < 4; ++nt) {
            const short8 bw = *(const short8*)(wqp + nt * 16 * 512 + ks * 32);
            qacc[0][nt] = __builtin_amdgcn_mfma_f32_16x16x32_bf16(ax0, bw, qacc[0][nt], 0, 0, 0);
            qacc[1][nt] = __builtin_amdgcn_mfma_f32_16x16x32_bf16(ax1, bw, qacc[1][nt], 0, 0, 0);
        }
    }
    #pragma unroll
    for (int g = 0; g < 2; ++g)
        #pragma unroll
        for (int nt = 0; nt < 4; ++nt)
            #pragma unroll
            for (int r = 0; r < 4; ++r)
                Pp[qr0 + g * 16 + q * 4 + r][nt * 16 + ln] = f2bf(qacc[g][nt][r]);
    asm volatile("s_waitcnt lgkmcnt(0)" ::: "memory");   // wave-private round trip
    short8 bq[2][2];
    #pragma unroll
    for (int g = 0; g < 2; ++g) {
        bq[g][0] = *(const short8*)&Pp[qr0 + g * 16 + ln][q * 8];
        bq[g][1] = *(const short8*)&Pp[qr0 + g * 16 + ln][q * 8 + 32];
    }

    // --- flash state in base-2 domain (per q-col = ln, per group g)
    float m_run[2] = {-1e30f, -1e30f}, l_run[2] = {0.f, 0.f};
    f32x4 o[2][4];
    #pragma unroll
    for (int g = 0; g < 2; ++g)
        #pragma unroll
        for (int j = 0; j < 4; ++j) o[g][j] = zero;

    for (int c = 0; c < 4; ++c) {
        // store staged chunk (regs were prefetched)
        *(short8*)&Ks[ksr][ksc]      = kp0;  *(short8*)&Ks[ksr][ksc + 8]  = kp1;
        *(short8*)&Ks[ksr][ksc + 16] = kp2;  *(short8*)&Ks[ksr][ksc + 24] = kp3;
        *(short8*)&Vs[vsr][vsc]      = vp0;  *(short8*)&Vs[vsr][vsc + 8]  = vp1;
        *(short8*)&Vs[vsr][vsc + 16] = vp2;  *(short8*)&Vs[vsr][vsc + 24] = vp3;
        __syncthreads();   // A: Ks/Vs ready

        // scores (transposed, pre-scaled by 0.125*log2e):
        // St[s = mt*16+quad*4+r][qcol = g*16+ln]
        f32x4 st[8][2];
        #pragma unroll
        for (int mt = 0; mt < 8; ++mt) {
            const short8 ak0 = *(const short8*)&Ks[mt * 16 + ln][q * 8];
            const short8 ak1 = *(const short8*)&Ks[mt * 16 + ln][q * 8 + 32];
            #pragma unroll
            for (int g = 0; g < 2; ++g) {
                f32x4 a = zero;
                a = __builtin_amdgcn_mfma_f32_16x16x32_bf16(ak0, bq[g][0], a, 0, 0, 0);
                a = __builtin_amdgcn_mfma_f32_16x16x32_bf16(ak1, bq[g][1], a, 0, 0, 0);
                #pragma unroll
                for (int r = 0; r < 4; ++r) a[r] *= SCALE2;
                st[mt][g] = a;
            }
        }

        // online softmax (base-2): max, alpha, exp2 + cvt_pk pack, l fold
        float alpha_[2];
        #pragma unroll
        for (int g = 0; g < 2; ++g) {
            float mx = st[0][g][0];
            #pragma unroll
            for (int mt = 0; mt < 8; ++mt)
                #pragma unroll
                for (int r = 0; r < 4; ++r) mx = fmaxf(mx, st[mt][g][r]);
            mx = fmaxf(mx, __shfl_xor(mx, 16));
            mx = fmaxf(mx, __shfl_xor(mx, 32));
            const float m_new = fmaxf(m_run[g], mx);
            alpha_[g] = __builtin_amdgcn_exp2f(m_run[g] - m_new);
            m_run[g] = m_new;
            float ls = 0.f;
            #pragma unroll
            for (int mt = 0; mt < 8; ++mt) {
                const float p0 = __builtin_amdgcn_exp2f(st[mt][g][0] - m_new);
                const float p1 = __builtin_amdgcn_exp2f(st[mt][g][1] - m_new);
                const float p2 = __builtin_amdgcn_exp2f(st[mt][g][2] - m_new);
                const float p3 = __builtin_amdgcn_exp2f(st[mt][g][3] - m_new);
                ls += (p0 + p1) + (p2 + p3);
                uint2 pw;
                pw.x = cvt_pk_bf16(p0, p1);
                pw.y = cvt_pk_bf16(p2, p3);
                *(uint2*)&Pp[qr0 + g * 16 + ln][mt * 16 + q * 4] = pw;
            }
            ls += __shfl_xor(ls, 16);
            ls += __shfl_xor(ls, 32);
            l_run[g] = l_run[g] * alpha_[g] + ls;
        }

        // rescale O (rows q' = quad*4+r of tile g)
        #pragma unroll
        for (int g = 0; g < 2; ++g) {
            #pragma unroll
            for (int r = 0; r < 4; ++r) {
                const float ab = __shfl(alpha_[g], q * 4 + r);
                #pragma unroll
                for (int j = 0; j < 4; ++j) o[g][j][r] *= ab;
            }
        }

        // prefetch next chunk into regs (overlaps PV)
        if (c < 3) {
            const unsigned short* ks = kgb + (size_t)((c + 1) * 128 + ksr) * 512 + ksc;
            kp0 = *(const short8*)ks;        kp1 = *(const short8*)(ks + 8);
            kp2 = *(const short8*)(ks + 16); kp3 = *(const short8*)(ks + 24);
            const unsigned short* vs = vtb + (size_t)vsr * SK + (c + 1) * 128 + vsc;
            vp0 = *(const short8*)vs;        vp1 = *(const short8*)(vs + 8);
            vp2 = *(const short8*)(vs + 16); vp3 = *(const short8*)(vs + 24);
        }

        asm volatile("s_waitcnt lgkmcnt(0)" ::: "memory");   // P visible to wave

        // PV: A = P rows (q), B = Vs rows (d), k = 128 chunk
        #pragma unroll
        for (int ks2 = 0; ks2 < 4; ++ks2) {
            const short8 ap0 = *(const short8*)&Pp[qr0 + ln][ks2 * 32 + q * 8];
            const short8 ap1 = *(const short8*)&Pp[qr0 + 16 + ln][ks2 * 32 + q * 8];
            #pragma unroll
            for (int j = 0; j < 4; ++j) {
                const short8 bv = *(const short8*)&Vs[j * 16 + ln][ks2 * 32 + q * 8];
                o[0][j] = __builtin_amdgcn_mfma_f32_16x16x32_bf16(ap0, bv, o[0][j], 0, 0, 0);
                o[1][j] = __builtin_amdgcn_mfma_f32_16x16x32_bf16(ap1, bv, o[1][j], 0, 0, 0);
            }
        }
        __syncthreads();   // B: Ks/Vs reads done before restage
    }

    // epilogue: scale by 1/l, store rows l0+qr0+g*16+q*4+r (+1 pad offset)
    #pragma unroll
    for (int g = 0; g < 2; ++g) {
        const float li = 1.f / l_run[g];
        #pragma unroll
        for (int r = 0; r < 4; ++r) {
            const float ib = __shfl(li, q * 4 + r);
            const int rl = qr0 + g * 16 + q * 4 + r;
            #pragma unroll
            for (int j = 0; j < 4; ++j)
                attpad[((size_t)b * PADROW) + (size_t)(l0 + rl + 1) * 512 + h * 64 + j * 16 + ln]
                    = f2bf(o[g][j][r] * ib);
        }
    }
}

// ---------------------------------------------------------------- launcher
extern "C" void kernel_launch(void* const* d_in, const int* in_sizes, int n_in,
                              void* d_out, int out_size, void* d_ws, size_t ws_size,
                              hipStream_t stream)
{
    const float* x    = (const float*)d_in[0];
    const float* Wq   = (const float*)d_in[1];
    const float* Wk   = (const float*)d_in[2];
    const float* Wv   = (const float*)d_in[3];
    const float* cw   = (const float*)d_in[4];   // [1536][512] flat fp32
    const float* cb   = (const float*)d_in[5];
    const float* mw   = (const float*)d_in[6];
    const float* mb2  = (const float*)d_in[7];
    const int*   sidx = (const int*)d_in[8];
    float* out = (float*)d_out;

    char* ws = (char*)d_ws;
    unsigned short* xb    = (unsigned short*)(ws + 0);           // 33,554,432 B
    unsigned short* Pool  = (unsigned short*)(ws + 0);           // alias (xb dead post-attn)
    unsigned short* Pad   = (unsigned short*)(ws + 33554432);    // 33,570,816 B
    unsigned short* xkg   = (unsigned short*)(ws + 33554432);    // alias Pad head
    unsigned short* xvg   = (unsigned short*)(ws + 37748736);    // alias
    unsigned short* Vg    = (unsigned short*)(ws + 41943040);    // alias
    unsigned short* Kg    = (unsigned short*)(ws + 67125248);    //  4,194,304 B
    unsigned short* Vt    = (unsigned short*)(ws + 71319552);    //  4,194,304 B
    unsigned short* WqT   = (unsigned short*)(ws + 75513856);    //    524,288 B
    unsigned short* WkT   = (unsigned short*)(ws + 76038144);
    unsigned short* WvT   = (unsigned short*)(ws + 76562432);
    unsigned short* CombT = (unsigned short*)(ws + 77086720);
    unsigned short* ConvT = (unsigned short*)(ws + 77611008);    // 1,572,864 B -> end 79,183,872

    dim3 blk(256);

    // 0. x -> bf16
    cvt_bf16<<<dim3(8192), blk, 0, stream>>>(x, xb);

    // 1. weight transposes (fp32 -> bf16): dst[N][K] = W[K][N]
    tr_f32_bf16<<<dim3(8, 8),  blk, 0, stream>>>(WqT,   Wq, 512, 512);
    tr_f32_bf16<<<dim3(8, 8),  blk, 0, stream>>>(WkT,   Wk, 512, 512);
    tr_f32_bf16<<<dim3(8, 8),  blk, 0, stream>>>(WvT,   Wv, 512, 512);
    tr_f32_bf16<<<dim3(8, 8),  blk, 0, stream>>>(CombT, mw, 512, 512);
    tr_f32_bf16<<<dim3(8, 24), blk, 0, stream>>>(ConvT, cw, 1536, 512);

    // 2. gathers (xkg/xvg in Pad head; consumed before zero_pad/attn)
    gather_rows<<<dim3(4096), blk, 0, stream>>>(xb, sidx, xkg, xvg);

    // 3. K/V projections (per-batch 512 gathered rows)
    gemm128<0><<<dim3(4, 32), blk, 0, stream>>>(xkg, WkT, nullptr, Kg, 512);
    gemm128<0><<<dim3(4, 32), blk, 0, stream>>>(xvg, WvT, nullptr, Vg, 512);

    // 4. Vt[b][e][s] = Vg[b][s][e]
    tr_bf16<<<dim3(8, 8, 8), blk, 0, stream>>>(Vt, Vg, 512, 512);

    // 5. attention (M=128 flash, LDS-shared K/V; writes Pad rows 1..L)
    zero_pad<<<dim3(16), blk, 0, stream>>>(Pad);
    attn_fused<<<dim3(32, 8, 8), blk, 0, stream>>>(xb, WqT, Kg, Vt, Pad);

    // 6. conv (K=1536) + bias + ELU + pool -> Pool (BN=256, XCD-colocated)
    gemm256n<<<dim3(512), blk, 0, stream>>>(Pad, ConvT, cb, Pool, 1536);

    // 7. final dense + bias -> out (fp32)
    gemm128<2><<<dim3(4, 128), blk, 0, stream>>>(Pool, CombT, mb2, out, 512);
}

// Round 13
// 355.199 us; speedup vs baseline: 1.1686x; 1.1209x over previous
//
#include <hip/hip_runtime.h>

// ProbAttention on MI355X (gfx950). Inputs/outputs fp32; compute in bf16 MFMA
// (mfma_f32_16x16x32_bf16, fp32 accumulate). B=8, L=4096, D=512, H=8, DK=64,
// S=512, CONV_K=3, POOL=2.
//
// v13 (resubmit; round-12 bench was an infra failure — container acquire):
// conv reverted to gemm128<1> (v12's BN=256 gemm256n was +16.5us SLOWER:
// halving A re-reads bought nothing — L3 already absorbed them (FETCH 187MB)
// — while the grid halved to 2 blocks/CU and per-barrier load depth rose,
// reducing TLP against the same barrier-drain latency). Launch-graph slimming
// instead (13 -> 9 dispatches, all numerics bit-identical):
//  - tr4_f32_bf16: the 4 square weight transposes merged into one (8,8,4)
//    dispatch (z selects matrix).
//  - gemm_proj: gather_rows FUSED into the K/V projections (grid (4,32,2),
//    z=0 K-proj via pv-chain, z=1 V-proj via qv). A rows are read from xb
//    through the sidx indirection (global_load_lds source is per-lane, so
//    indirected row bases are free); eliminates the gather kernel and the
//    16.8 MB xkg/xvg round-trip; one full-GPU proj dispatch instead of two
//    half-GPU ones. Same clip semantics as gather_rows -> bit-identical.

typedef __attribute__((ext_vector_type(8))) short  short8;
typedef __attribute__((ext_vector_type(4))) short  short4b;
typedef __attribute__((ext_vector_type(4))) float  f32x4;

#define LSEQ   4096
#define SK     512
#define EDIM   512
#define LPAD   4098            // L + 2
#define PADROW 2098176         // LPAD * 512 (shorts)
#define SCALE2 0.180336880f    // 0.125 * log2(e) — fp32 score scale for exp2

static __device__ __forceinline__ float bf2f(unsigned short h) {
    union { unsigned int u; float f; } v; v.u = ((unsigned int)h) << 16; return v.f;
}
static __device__ __forceinline__ unsigned short f2bf(float f) {
    union { float f; unsigned int u; } v; v.f = f;
    unsigned int r = (v.u + 0x7fffu + ((v.u >> 16) & 1u)) >> 16;
    return (unsigned short)r;
}
static __device__ __forceinline__ unsigned int cvt_pk_bf16(float lo, float hi) {
    unsigned int r;
    asm("v_cvt_pk_bf16_f32 %0, %1, %2" : "=v"(r) : "v"(lo), "v"(hi));
    return r;   // dst[15:0] = bf16(lo), dst[31:16] = bf16(hi)
}
// async global -> LDS, 16 B per lane; LDS dest = wave-uniform base + lane*16
typedef __attribute__((address_space(1))) const unsigned int  gu32;
typedef __attribute__((address_space(3))) unsigned int        lu32;
static __device__ __forceinline__ void g2l16(const unsigned short* g, unsigned short* l)
{
    __builtin_amdgcn_global_load_lds((gu32*)g, (lu32*)l, 16, 0, 0);
}

// ---------------------------------------------------------------- fp32 -> bf16
__global__ __launch_bounds__(256)
void cvt_bf16(const float* __restrict__ src, unsigned short* __restrict__ dst)
{
    const size_t i = ((size_t)blockIdx.x * 256 + threadIdx.x) * 8;
    const float4 a = *(const float4*)(src + i);
    const float4 b = *(const float4*)(src + i + 4);
    short8 o;
    o[0] = (short)f2bf(a.x); o[1] = (short)f2bf(a.y);
    o[2] = (short)f2bf(a.z); o[3] = (short)f2bf(a.w);
    o[4] = (short)f2bf(b.x); o[5] = (short)f2bf(b.y);
    o[6] = (short)f2bf(b.z); o[7] = (short)f2bf(b.w);
    *(short8*)(dst + i) = o;
}

// ---------------------------------------------------------------- transpose fp32 -> bf16 (generic)
__global__ __launch_bounds__(256)
void tr_f32_bf16(unsigned short* __restrict__ dst, const float* __restrict__ src,
                 int R, int C)
{
    __shared__ unsigned short T[64][72];
    const int t  = threadIdx.x;
    const int r0 = blockIdx.y * 64, c0 = blockIdx.x * 64;
    const int row = t >> 2, cg = (t & 3) * 16;
    const float* s = src + (size_t)(r0 + row) * C + c0 + cg;
    const float4 f0 = *(const float4*)s;
    const float4 f1 = *(const float4*)(s + 4);
    const float4 f2 = *(const float4*)(s + 8);
    const float4 f3 = *(const float4*)(s + 12);
    T[row][cg + 0]  = f2bf(f0.x); T[row][cg + 1]  = f2bf(f0.y);
    T[row][cg + 2]  = f2bf(f0.z); T[row][cg + 3]  = f2bf(f0.w);
    T[row][cg + 4]  = f2bf(f1.x); T[row][cg + 5]  = f2bf(f1.y);
    T[row][cg + 6]  = f2bf(f1.z); T[row][cg + 7]  = f2bf(f1.w);
    T[row][cg + 8]  = f2bf(f2.x); T[row][cg + 9]  = f2bf(f2.y);
    T[row][cg + 10] = f2bf(f2.z); T[row][cg + 11] = f2bf(f2.w);
    T[row][cg + 12] = f2bf(f3.x); T[row][cg + 13] = f2bf(f3.y);
    T[row][cg + 14] = f2bf(f3.z); T[row][cg + 15] = f2bf(f3.w);
    __syncthreads();
    unsigned short* d = dst + (size_t)(c0 + row) * R + r0 + cg;
    short8 o0, o1;
    #pragma unroll
    for (int k = 0; k < 8; ++k) o0[k] = (short)T[cg + k][row];
    #pragma unroll
    for (int k = 0; k < 8; ++k) o1[k] = (short)T[cg + 8 + k][row];
    *(short8*)d       = o0;
    *(short8*)(d + 8) = o1;
}

// ---------------------------------------------------------------- 4x 512x512 transpose fp32 -> bf16
__global__ __launch_bounds__(256)
void tr4_f32_bf16(const float* __restrict__ s0, const float* __restrict__ s1,
                  const float* __restrict__ s2, const float* __restrict__ s3,
                  unsigned short* __restrict__ d0, unsigned short* __restrict__ d1,
                  unsigned short* __restrict__ d2, unsigned short* __restrict__ d3)
{
    __shared__ unsigned short T[64][72];
    const float* src; unsigned short* dst;
    switch (blockIdx.z) {
        case 0:  src = s0; dst = d0; break;
        case 1:  src = s1; dst = d1; break;
        case 2:  src = s2; dst = d2; break;
        default: src = s3; dst = d3; break;
    }
    const int t  = threadIdx.x;
    const int r0 = blockIdx.y * 64, c0 = blockIdx.x * 64;
    const int row = t >> 2, cg = (t & 3) * 16;
    const float* s = src + (size_t)(r0 + row) * 512 + c0 + cg;
    const float4 f0 = *(const float4*)s;
    const float4 f1 = *(const float4*)(s + 4);
    const float4 f2 = *(const float4*)(s + 8);
    const float4 f3 = *(const float4*)(s + 12);
    T[row][cg + 0]  = f2bf(f0.x); T[row][cg + 1]  = f2bf(f0.y);
    T[row][cg + 2]  = f2bf(f0.z); T[row][cg + 3]  = f2bf(f0.w);
    T[row][cg + 4]  = f2bf(f1.x); T[row][cg + 5]  = f2bf(f1.y);
    T[row][cg + 6]  = f2bf(f1.z); T[row][cg + 7]  = f2bf(f1.w);
    T[row][cg + 8]  = f2bf(f2.x); T[row][cg + 9]  = f2bf(f2.y);
    T[row][cg + 10] = f2bf(f2.z); T[row][cg + 11] = f2bf(f2.w);
    T[row][cg + 12] = f2bf(f3.x); T[row][cg + 13] = f2bf(f3.y);
    T[row][cg + 14] = f2bf(f3.z); T[row][cg + 15] = f2bf(f3.w);
    __syncthreads();
    unsigned short* d = dst + (size_t)(c0 + row) * 512 + r0 + cg;
    short8 o0, o1;
    #pragma unroll
    for (int k = 0; k < 8; ++k) o0[k] = (short)T[cg + k][row];
    #pragma unroll
    for (int k = 0; k < 8; ++k) o1[k] = (short)T[cg + 8 + k][row];
    *(short8*)d       = o0;
    *(short8*)(d + 8) = o1;
}

// ---------------------------------------------------------------- transpose bf16
__global__ __launch_bounds__(256)
void tr_bf16(unsigned short* __restrict__ dst, const unsigned short* __restrict__ src,
             int R, int C)
{
    __shared__ unsigned short T[64][72];
    const size_t bofs = (size_t)blockIdx.z * (size_t)R * (size_t)C;
    src += bofs; dst += bofs;
    const int t  = threadIdx.x;
    const int r0 = blockIdx.y * 64, c0 = blockIdx.x * 64;
    const int row = t >> 2, cg = (t & 3) * 16;
    const unsigned short* s = src + (size_t)(r0 + row) * C + c0 + cg;
    *(short8*)&T[row][cg]     = *(const short8*)s;
    *(short8*)&T[row][cg + 8] = *(const short8*)(s + 8);
    __syncthreads();
    unsigned short* d = dst + (size_t)(c0 + row) * R + r0 + cg;
    short8 o0, o1;
    #pragma unroll
    for (int k = 0; k < 8; ++k) o0[k] = (short)T[cg + k][row];
    #pragma unroll
    for (int k = 0; k < 8; ++k) o1[k] = (short)T[cg + 8 + k][row];
    *(short8*)d       = o0;
    *(short8*)(d + 8) = o1;
}

// ---------------------------------------------------------------- zero pad rows
__global__ __launch_bounds__(256)
void zero_pad(unsigned short* __restrict__ attpad)
{
    const int i = blockIdx.x * 256 + threadIdx.x;   // 0..4095
    const int b = i >> 9, c = i & 511;
    attpad[(size_t)b * PADROW + c] = 0;
    attpad[(size_t)b * PADROW + (size_t)(LPAD - 1) * 512 + c] = 0;
}

// ---------------------------------------------------------------- GEMM 128x128x32
// MODE 0: bf16 store. MODE 1: conv epilogue (+bias, ELU, MaxPool2 -> bf16).
// MODE 2: +bias, fp32 store. global_load_lds double-buffer (v10-verified).
template<int MODE>
__global__ __launch_bounds__(256)
void gemm128(const unsigned short* __restrict__ A, const unsigned short* __restrict__ Bt,
             const float* __restrict__ bias, void* __restrict__ Cout, int K)
{
    __shared__ unsigned short As[2][128 * 32];
    __shared__ unsigned short Bs[2][128 * 32];
    const int t    = threadIdx.x;
    const int n0   = blockIdx.x * 128;
    const int m0   = blockIdx.y * 128;
    const int lane = t & 63, wv = t >> 6;
    const int q = lane >> 4, ln = lane & 15;
    const int wm = (wv & 1) * 64, wn = (wv >> 1) * 64;

    const int srl = (wv << 5) + (lane >> 2);     // rows srl and srl+16
    const int scs = (lane & 3) * 8;              // 16B column (shorts)
    const unsigned short* arow0;
    const unsigned short* arow1;
    if (MODE == 1) {
        const int gr0 = m0 + srl;                // block never straddles a batch
        arow0 = A + (size_t)(gr0 >> 12) * PADROW + (size_t)(gr0 & 4095) * 512 + scs;
        arow1 = arow0 + (size_t)16 * 512;
    } else {
        arow0 = A + (size_t)(m0 + srl) * K + scs;
        arow1 = arow0 + (size_t)16 * K;
    }
    const unsigned short* brow0 = Bt + (size_t)(n0 + srl) * K + scs;
    const unsigned short* brow1 = brow0 + (size_t)16 * K;

    const int lb0 = (wv << 5) * 32;
    const int lb1 = lb0 + 16 * 32;

    const f32x4 zero = {0.f, 0.f, 0.f, 0.f};
    f32x4 acc[4][4];
    #pragma unroll
    for (int i = 0; i < 4; ++i)
        #pragma unroll
        for (int j = 0; j < 4; ++j) acc[i][j] = zero;

    g2l16(arow0, &As[0][lb0]);  g2l16(arow1, &As[0][lb1]);
    g2l16(brow0, &Bs[0][lb0]);  g2l16(brow1, &Bs[0][lb1]);

    for (int k0 = 0; k0 < K; k0 += 32) {
        const int cur = (k0 >> 5) & 1;
        __syncthreads();   // drains vmcnt: buf[cur] staged; prev reads done
        if (k0 + 32 < K) {
            const int nxt = cur ^ 1;
            g2l16(arow0 + k0 + 32, &As[nxt][lb0]);
            g2l16(arow1 + k0 + 32, &As[nxt][lb1]);
            g2l16(brow0 + k0 + 32, &Bs[nxt][lb0]);
            g2l16(brow1 + k0 + 32, &Bs[nxt][lb1]);
        }
        short8 af[4], bf[4];
        #pragma unroll
        for (int mt = 0; mt < 4; ++mt)
            af[mt] = *(const short8*)&As[cur][(wm + mt * 16 + ln) * 32 + q * 8];
        #pragma unroll
        for (int nt = 0; nt < 4; ++nt)
            bf[nt] = *(const short8*)&Bs[cur][(wn + nt * 16 + ln) * 32 + q * 8];
        #pragma unroll
        for (int mt = 0; mt < 4; ++mt)
            #pragma unroll
            for (int nt = 0; nt < 4; ++nt)
                acc[mt][nt] = __builtin_amdgcn_mfma_f32_16x16x32_bf16(af[mt], bf[nt], acc[mt][nt], 0, 0, 0);
    }

    if (MODE == 0) {
        unsigned short* C = (unsigned short*)Cout;
        #pragma unroll
        for (int mt = 0; mt < 4; ++mt)
            #pragma unroll
            for (int r = 0; r < 4; ++r) {
                const int grow = m0 + wm + mt * 16 + q * 4 + r;
                unsigned short* cp = C + (size_t)grow * 512 + n0 + wn + ln;
                #pragma unroll
                for (int nt = 0; nt < 4; ++nt) cp[nt * 16] = f2bf(acc[mt][nt][r]);
            }
    } else if (MODE == 2) {
        float* C = (float*)Cout;
        float bb[4];
        #pragma unroll
        for (int nt = 0; nt < 4; ++nt) bb[nt] = bias[n0 + wn + nt * 16 + ln];
        #pragma unroll
        for (int mt = 0; mt < 4; ++mt)
            #pragma unroll
            for (int r = 0; r < 4; ++r) {
                const int grow = m0 + wm + mt * 16 + q * 4 + r;
                float* cp = C + (size_t)grow * 512 + n0 + wn + ln;
                #pragma unroll
                for (int nt = 0; nt < 4; ++nt) cp[nt * 16] = acc[mt][nt][r] + bb[nt];
            }
    } else { // MODE 1
        unsigned short* C = (unsigned short*)Cout;
        float bb[4];
        #pragma unroll
        for (int nt = 0; nt < 4; ++nt) bb[nt] = bias[n0 + wn + nt * 16 + ln];
        #pragma unroll
        for (int mt = 0; mt < 4; ++mt) {
            const int grow = m0 + wm + mt * 16 + q * 4;
            const int b = grow >> 12, l = grow & 4095;
            unsigned short* cp = C + ((size_t)b * 2048 + (l >> 1)) * 512 + n0 + wn + ln;
            #pragma unroll
            for (int nt = 0; nt < 4; ++nt) {
                float v0 = acc[mt][nt][0] + bb[nt]; v0 = v0 > 0.f ? v0 : __expf(v0) - 1.f;
                float v1 = acc[mt][nt][1] + bb[nt]; v1 = v1 > 0.f ? v1 : __expf(v1) - 1.f;
                float v2 = acc[mt][nt][2] + bb[nt]; v2 = v2 > 0.f ? v2 : __expf(v2) - 1.f;
                float v3 = acc[mt][nt][3] + bb[nt]; v3 = v3 > 0.f ? v3 : __expf(v3) - 1.f;
                cp[nt * 16]       = f2bf(fmaxf(v0, v1));
                cp[512 + nt * 16] = f2bf(fmaxf(v2, v3));
            }
        }
    }
}

// ---------------------------------------------------------------- fused gather + K/V projection
// grid (4, 32, 2): z=0 K-proj (pv index chain, B=WkT, C=Kg); z=1 V-proj
// (qv chain, B=WvT, C=Vg). Identical GEMM body to gemm128 MODE 0, but the
// A rows are read from xb through the sidx indirection (exact gather_rows
// clip semantics), eliminating the separate gather kernel and buffers.
__global__ __launch_bounds__(256)
void gemm_proj(const unsigned short* __restrict__ xb, const int* __restrict__ sidx,
               const unsigned short* __restrict__ WkT, const unsigned short* __restrict__ WvT,
               unsigned short* __restrict__ Kg, unsigned short* __restrict__ Vg)
{
    __shared__ unsigned short As[2][128 * 32];
    __shared__ unsigned short Bs[2][128 * 32];
    const int K    = 512;
    const int t    = threadIdx.x;
    const int z    = blockIdx.z;
    const int n0   = blockIdx.x * 128;
    const int m0   = blockIdx.y * 128;
    const int lane = t & 63, wv = t >> 6;
    const int q = lane >> 4, ln = lane & 15;
    const int wm = (wv & 1) * 64, wn = (wv >> 1) * 64;

    const unsigned short* Bt = z == 0 ? WkT : WvT;
    unsigned short* C        = z == 0 ? Kg  : Vg;

    const int srl = (wv << 5) + (lane >> 2);
    const int scs = (lane & 3) * 8;
    // gathered-row indirection (gather_rows semantics, bit-identical)
    const unsigned short* arow[2];
    #pragma unroll
    for (int i = 0; i < 2; ++i) {
        const int gr = m0 + srl + i * 16;        // in [0, 4096)
        const int b = gr >> 9, j = gr & 511;
        int qv = sidx[j];  qv = qv < 0 ? 0 : (qv > LSEQ - 1 ? LSEQ - 1 : qv);
        int idx = qv;
        if (z == 0) {
            const int cv = qv < SK - 1 ? qv : SK - 1;
            int pv = sidx[cv];  pv = pv < 0 ? 0 : (pv > LSEQ - 1 ? LSEQ - 1 : pv);
            idx = pv;
        }
        arow[i] = xb + ((size_t)b * LSEQ + idx) * 512 + scs;
    }
    const unsigned short* brow0 = Bt + (size_t)(n0 + srl) * K + scs;
    const unsigned short* brow1 = brow0 + (size_t)16 * K;

    const int lb0 = (wv << 5) * 32;
    const int lb1 = lb0 + 16 * 32;

    const f32x4 zero = {0.f, 0.f, 0.f, 0.f};
    f32x4 acc[4][4];
    #pragma unroll
    for (int i = 0; i < 4; ++i)
        #pragma unroll
        for (int j = 0; j < 4; ++j) acc[i][j] = zero;

    g2l16(arow[0], &As[0][lb0]);  g2l16(arow[1], &As[0][lb1]);
    g2l16(brow0, &Bs[0][lb0]);    g2l16(brow1, &Bs[0][lb1]);

    for (int k0 = 0; k0 < K; k0 += 32) {
        const int cur = (k0 >> 5) & 1;
        __syncthreads();
        if (k0 + 32 < K) {
            const int nxt = cur ^ 1;
            g2l16(arow[0] + k0 + 32, &As[nxt][lb0]);
            g2l16(arow[1] + k0 + 32, &As[nxt][lb1]);
            g2l16(brow0 + k0 + 32, &Bs[nxt][lb0]);
            g2l16(brow1 + k0 + 32, &Bs[nxt][lb1]);
        }
        short8 af[4], bf[4];
        #pragma unroll
        for (int mt = 0; mt < 4; ++mt)
            af[mt] = *(const short8*)&As[cur][(wm + mt * 16 + ln) * 32 + q * 8];
        #pragma unroll
        for (int nt = 0; nt < 4; ++nt)
            bf[nt] = *(const short8*)&Bs[cur][(wn + nt * 16 + ln) * 32 + q * 8];
        #pragma unroll
        for (int mt = 0; mt < 4; ++mt)
            #pragma unroll
            for (int nt = 0; nt < 4; ++nt)
                acc[mt][nt] = __builtin_amdgcn_mfma_f32_16x16x32_bf16(af[mt], bf[nt], acc[mt][nt], 0, 0, 0);
    }

    #pragma unroll
    for (int mt = 0; mt < 4; ++mt)
        #pragma unroll
        for (int r = 0; r < 4; ++r) {
            const int grow = m0 + wm + mt * 16 + q * 4 + r;
            unsigned short* cp = C + (size_t)grow * 512 + n0 + wn + ln;
            #pragma unroll
            for (int nt = 0; nt < 4; ++nt) cp[nt * 16] = f2bf(acc[mt][nt][r]);
        }
}

// ---------------------------------------------------------------- fused attention v9
// grid (L/128, H, B), 256 threads = 4 waves; wave w owns 32 q-rows (2 tiles).
// S in 4 chunks of 128, online softmax in base-2 domain; P packed with
// v_cvt_pk_bf16_f32. K chunk (128x64) and V chunk (64x128) in LDS shared by
// all 4 waves; next chunk register-prefetched during softmax/PV; full-width
// Pp round-trip, ONE lgkmcnt drain + one PV sweep per chunk.
// LDS = 18,432 + 17,408 + 34,816 = 70,656 B (2 blocks/CU).
__global__ __launch_bounds__(256, 2)
void attn_fused(const unsigned short* __restrict__ xb, const unsigned short* __restrict__ WqT,
                const unsigned short* __restrict__ Kg, const unsigned short* __restrict__ Vt,
                unsigned short* __restrict__ attpad)
{
    __shared__ unsigned short Ks[128][72];
    __shared__ unsigned short Vs[64][136];
    __shared__ unsigned short Pp[128][136];   // P per chunk; also Q round-trip
    const int t = threadIdx.x;
    const int wv = t >> 6, lane = t & 63, q = lane >> 4, ln = lane & 15;
    const int l0 = blockIdx.x * 128, h = blockIdx.y, b = blockIdx.z;
    const int qr0 = wv * 32;
    const f32x4 zero = {0.f, 0.f, 0.f, 0.f};

    // staging maps
    const unsigned short* kgb = Kg + (size_t)b * SK * 512 + h * 64;        // + s*512 + e
    const unsigned short* vtb = Vt + ((size_t)(b * EDIM + h * 64)) * SK;   // + d*SK + s
    const int ksr = t >> 1, ksc = (t & 1) * 32;    // K: row s, 32-short half
    const int vsr = t >> 2, vsc = (t & 3) * 32;    // V: row d, 32-short quarter

    // prefetch chunk 0 (flies during Q projection)
    short8 kp0, kp1, kp2, kp3, vp0, vp1, vp2, vp3;
    {
        const unsigned short* ks = kgb + (size_t)ksr * 512 + ksc;
        kp0 = *(const short8*)ks;        kp1 = *(const short8*)(ks + 8);
        kp2 = *(const short8*)(ks + 16); kp3 = *(const short8*)(ks + 24);
        const unsigned short* vs = vtb + (size_t)vsr * SK + vsc;
        vp0 = *(const short8*)vs;        vp1 = *(const short8*)(vs + 8);
        vp2 = *(const short8*)(vs + 16); vp3 = *(const short8*)(vs + 24);
    }

    // --- Q projection: rows qr0 + g*16 + ln (g=0,1), 64 head cols, k=512
    f32x4 qacc[2][4];
    #pragma unroll
    for (int g = 0; g < 2; ++g)
        #pragma unroll
        for (int nt = 0; nt < 4; ++nt) qacc[g][nt] = zero;
    const unsigned short* xr0 = xb + ((size_t)(b * LSEQ + l0 + qr0 + ln)) * 512 + q * 8;
    const unsigned short* xr1 = xr0 + (size_t)16 * 512;
    const unsigned short* wqp = WqT + ((size_t)(h * 64 + ln)) * 512 + q * 8;
    for (int ks = 0; ks < 16; ++ks) {
        const short8 ax0 = *(const short8*)(xr0 + ks * 32);
        const short8 ax1 = *(const short8*)(xr1 + ks * 32);
        #pragma unroll
        for (int nt = 0; nt < 4; ++nt) {
            const short8 bw = *(const short8*)(wqp + nt * 16 * 512 + ks * 32);
            qacc[0][nt] = __builtin_amdgcn_mfma_f32_16x16x32_bf16(ax0, bw, qacc[0][nt], 0, 0, 0);
            qacc[1][nt] = __builtin_amdgcn_mfma_f32_16x16x32_bf16(ax1, bw, qacc[1][nt], 0, 0, 0);
        }
    }
    #pragma unroll
    for (int g = 0; g < 2; ++g)
        #pragma unroll
        for (int nt = 0; nt < 4; ++nt)
            #pragma unroll
            for (int r = 0; r < 4; ++r)
                Pp[qr0 + g * 16 + q * 4 + r][nt * 16 + ln] = f2bf(qacc[g][nt][r]);
    asm volatile("s_waitcnt lgkmcnt(0)" ::: "memory");   // wave-private round trip
    short8 bq[2][2];
    #pragma unroll
    for (int g = 0; g < 2; ++g) {
        bq[g][0] = *(const short8*)&Pp[qr0 + g * 16 + ln][q * 8];
        bq[g][1] = *(const short8*)&Pp[qr0 + g * 16 + ln][q * 8 + 32];
    }

    // --- flash state in base-2 domain (per q-col = ln, per group g)
    float m_run[2] = {-1e30f, -1e30f}, l_run[2] = {0.f, 0.f};
    f32x4 o[2][4];
    #pragma unroll
    for (int g = 0; g < 2; ++g)
        #pragma unroll
        for (int j = 0; j < 4; ++j) o[g][j] = zero;

    for (int c = 0; c < 4; ++c) {
        // store staged chunk (regs were prefetched)
        *(short8*)&Ks[ksr][ksc]      = kp0;  *(short8*)&Ks[ksr][ksc + 8]  = kp1;
        *(short8*)&Ks[ksr][ksc + 16] = kp2;  *(short8*)&Ks[ksr][ksc + 24] = kp3;
        *(short8*)&Vs[vsr][vsc]      = vp0;  *(short8*)&Vs[vsr][vsc + 8]  = vp1;
        *(short8*)&Vs[vsr][vsc + 16] = vp2;  *(short8*)&Vs[vsr][vsc + 24] = vp3;
        __syncthreads();   // A: Ks/Vs ready

        // scores (transposed, pre-scaled by 0.125*log2e):
        // St[s = mt*16+quad*4+r][qcol = g*16+ln]
        f32x4 st[8][2];
        #pragma unroll
        for (int mt = 0; mt < 8; ++mt) {
            const short8 ak0 = *(const short8*)&Ks[mt * 16 + ln][q * 8];
            const short8 ak1 = *(const short8*)&Ks[mt * 16 + ln][q * 8 + 32];
            #pragma unroll
            for (int g = 0; g < 2; ++g) {
                f32x4 a = zero;
                a = __builtin_amdgcn_mfma_f32_16x16x32_bf16(ak0, bq[g][0], a, 0, 0, 0);
                a = __builtin_amdgcn_mfma_f32_16x16x32_bf16(ak1, bq[g][1], a, 0, 0, 0);
                #pragma unroll
                for (int r = 0; r < 4; ++r) a[r] *= SCALE2;
                st[mt][g] = a;
            }
        }

        // online softmax (base-2): max, alpha, exp2 + cvt_pk pack, l fold
        float alpha_[2];
        #pragma unroll
        for (int g = 0; g < 2; ++g) {
            float mx = st[0][g][0];
            #pragma unroll
            for (int mt = 0; mt < 8; ++mt)
                #pragma unroll
                for (int r = 0; r < 4; ++r) mx = fmaxf(mx, st[mt][g][r]);
            mx = fmaxf(mx, __shfl_xor(mx, 16));
            mx = fmaxf(mx, __shfl_xor(mx, 32));
            const float m_new = fmaxf(m_run[g], mx);
            alpha_[g] = __builtin_amdgcn_exp2f(m_run[g] - m_new);
            m_run[g] = m_new;
            float ls = 0.f;
            #pragma unroll
            for (int mt = 0; mt < 8; ++mt) {
                const float p0 = __builtin_amdgcn_exp2f(st[mt][g][0] - m_new);
                const float p1 = __builtin_amdgcn_exp2f(st[mt][g][1] - m_new);
                const float p2 = __builtin_amdgcn_exp2f(st[mt][g][2] - m_new);
                const float p3 = __builtin_amdgcn_exp2f(st[mt][g][3] - m_new);
                ls += (p0 + p1) + (p2 + p3);
                uint2 pw;
                pw.x = cvt_pk_bf16(p0, p1);
                pw.y = cvt_pk_bf16(p2, p3);
                *(uint2*)&Pp[qr0 + g * 16 + ln][mt * 16 + q * 4] = pw;
            }
            ls += __shfl_xor(ls, 16);
            ls += __shfl_xor(ls, 32);
            l_run[g] = l_run[g] * alpha_[g] + ls;
        }

        // rescale O (rows q' = quad*4+r of tile g)
        #pragma unroll
        for (int g = 0; g < 2; ++g) {
            #pragma unroll
            for (int r = 0; r < 4; ++r) {
                const float ab = __shfl(alpha_[g], q * 4 + r);
                #pragma unroll
                for (int j = 0; j < 4; ++j) o[g][j][r] *= ab;
            }
        }

        // prefetch next chunk into regs (overlaps PV)
        if (c < 3) {
            const unsigned short* ks = kgb + (size_t)((c + 1) * 128 + ksr) * 512 + ksc;
            kp0 = *(const short8*)ks;        kp1 = *(const short8*)(ks + 8);
            kp2 = *(const short8*)(ks + 16); kp3 = *(const short8*)(ks + 24);
            const unsigned short* vs = vtb + (size_t)vsr * SK + (c + 1) * 128 + vsc;
            vp0 = *(const short8*)vs;        vp1 = *(const short8*)(vs + 8);
            vp2 = *(const short8*)(vs + 16); vp3 = *(const short8*)(vs + 24);
        }

        asm volatile("s_waitcnt lgkmcnt(0)" ::: "memory");   // P visible to wave

        // PV: A = P rows (q), B = Vs rows (d), k = 128 chunk
        #pragma unroll
        for (int ks2 = 0; ks2 < 4; ++ks2) {
            const short8 ap0 = *(const short8*)&Pp[qr0 + ln][ks2 * 32 + q * 8];
            const short8 ap1 = *(const short8*)&Pp[qr0 + 16 + ln][ks2 * 32 + q * 8];
            #pragma unroll
            for (int j = 0; j < 4; ++j) {
                const short8 bv = *(const short8*)&Vs[j * 16 + ln][ks2 * 32 + q * 8];
                o[0][j] = __builtin_amdgcn_mfma_f32_16x16x32_bf16(ap0, bv, o[0][j], 0, 0, 0);
                o[1][j] = __builtin_amdgcn_mfma_f32_16x16x32_bf16(ap1, bv, o[1][j], 0, 0, 0);
            }
        }
        __syncthreads();   // B: Ks/Vs reads done before restage
    }

    // epilogue: scale by 1/l, store rows l0+qr0+g*16+q*4+r (+1 pad offset)
    #pragma unroll
    for (int g = 0; g < 2; ++g) {
        const float li = 1.f / l_run[g];
        #pragma unroll
        for (int r = 0; r < 4; ++r) {
            const float ib = __shfl(li, q * 4 + r);
            const int rl = qr0 + g * 16 + q * 4 + r;
            #pragma unroll
            for (int j = 0; j < 4; ++j)
                attpad[((size_t)b * PADROW) + (size_t)(l0 + rl + 1) * 512 + h * 64 + j * 16 + ln]
                    = f2bf(o[g][j][r] * ib);
        }
    }
}

// ---------------------------------------------------------------- launcher
extern "C" void kernel_launch(void* const* d_in, const int* in_sizes, int n_in,
                              void* d_out, int out_size, void* d_ws, size_t ws_size,
                              hipStream_t stream)
{
    const float* x    = (const float*)d_in[0];
    const float* Wq   = (const float*)d_in[1];
    const float* Wk   = (const float*)d_in[2];
    const float* Wv   = (const float*)d_in[3];
    const float* cw   = (const float*)d_in[4];   // [1536][512] flat fp32
    const float* cb   = (const float*)d_in[5];
    const float* mw   = (const float*)d_in[6];
    const float* mb2  = (const float*)d_in[7];
    const int*   sidx = (const int*)d_in[8];
    float* out = (float*)d_out;

    char* ws = (char*)d_ws;
    unsigned short* xb    = (unsigned short*)(ws + 0);           // 33,554,432 B
    unsigned short* Pool  = (unsigned short*)(ws + 0);           // alias (xb dead post-attn)
    unsigned short* Pad   = (unsigned short*)(ws + 33554432);    // 33,570,816 B
    unsigned short* Vg    = (unsigned short*)(ws + 41943040);    // alias Pad interior (dead pre-attn)
    unsigned short* Kg    = (unsigned short*)(ws + 67125248);    //  4,194,304 B
    unsigned short* Vt    = (unsigned short*)(ws + 71319552);    //  4,194,304 B
    unsigned short* WqT   = (unsigned short*)(ws + 75513856);    //    524,288 B
    unsigned short* WkT   = (unsigned short*)(ws + 76038144);
    unsigned short* WvT   = (unsigned short*)(ws + 76562432);
    unsigned short* CombT = (unsigned short*)(ws + 77086720);
    unsigned short* ConvT = (unsigned short*)(ws + 77611008);    // 1,572,864 B -> end 79,183,872

    dim3 blk(256);

    // 0. x -> bf16
    cvt_bf16<<<dim3(8192), blk, 0, stream>>>(x, xb);

    // 1. weight transposes (fp32 -> bf16): one dispatch for the 4 square
    //    weights, one for the 1536x512 conv weight
    tr4_f32_bf16<<<dim3(8, 8, 4), blk, 0, stream>>>(Wq, Wk, Wv, mw,
                                                    WqT, WkT, WvT, CombT);
    tr_f32_bf16<<<dim3(8, 24), blk, 0, stream>>>(ConvT, cw, 1536, 512);

    // 2. fused gather + K/V projections (z=0: K via pv; z=1: V via qv)
    gemm_proj<<<dim3(4, 32, 2), blk, 0, stream>>>(xb, sidx, WkT, WvT, Kg, Vg);

    // 3. Vt[b][e][s] = Vg[b][s][e]
    tr_bf16<<<dim3(8, 8, 8), blk, 0, stream>>>(Vt, Vg, 512, 512);

    // 4. attention (M=128 flash, LDS-shared K/V; writes Pad rows 1..L)
    zero_pad<<<dim3(16), blk, 0, stream>>>(Pad);
    attn_fused<<<dim3(32, 8, 8), blk, 0, stream>>>(xb, WqT, Kg, Vt, Pad);

    // 5. conv (K=1536) + bias + ELU + pool -> Pool (aliases dead xb)
    gemm128<1><<<dim3(4, 256), blk, 0, stream>>>(Pad, ConvT, cb, Pool, 1536);

    // 6. final dense + bias -> out (fp32)
    gemm128<2><<<dim3(4, 128), blk, 0, stream>>>(Pool, CombT, mb2, out, 512);
}

// Round 14
// 351.102 us; speedup vs baseline: 1.1822x; 1.0117x over previous
//
#include <hip/hip_runtime.h>

// ProbAttention on MI355X (gfx950). Inputs/outputs fp32; compute in bf16 MFMA
// (mfma_f32_16x16x32_bf16, fp32 accumulate). B=8, L=4096, D=512, H=8, DK=64,
// S=512, CONV_K=3, POOL=2.
//
// v14: launch-graph slimming round 2 (9 -> 6 dispatches; ~8us/dispatch
// overhead measured via the v11 probe: +4 launches cost +33us).
//  - prep: cvt_bf16 (8192 blocks) + the 4 square weight transposes (256) +
//    the 1536x512 conv weight transpose (192) in ONE 8640-block dispatch
//    (block-uniform branch on blockIdx.x; all work independent).
//  - zero_pad folded into attn_fused: blocks (x==0,h==0) write batch b's two
//    pad rows. NOTE this is only legal AFTER tr_bf16 consumed Vg (the b=2
//    pad row overlaps the Vg alias inside Pad) — attn runs after tr_bf16,
//    and the kernel boundary orders the writes before conv's reads.
// All numerics bit-identical to v13 (355.2 us measured).

typedef __attribute__((ext_vector_type(8))) short  short8;
typedef __attribute__((ext_vector_type(4))) short  short4b;
typedef __attribute__((ext_vector_type(4))) float  f32x4;

#define LSEQ   4096
#define SK     512
#define EDIM   512
#define LPAD   4098            // L + 2
#define PADROW 2098176         // LPAD * 512 (shorts)
#define SCALE2 0.180336880f    // 0.125 * log2(e) — fp32 score scale for exp2

static __device__ __forceinline__ float bf2f(unsigned short h) {
    union { unsigned int u; float f; } v; v.u = ((unsigned int)h) << 16; return v.f;
}
static __device__ __forceinline__ unsigned short f2bf(float f) {
    union { float f; unsigned int u; } v; v.f = f;
    unsigned int r = (v.u + 0x7fffu + ((v.u >> 16) & 1u)) >> 16;
    return (unsigned short)r;
}
static __device__ __forceinline__ unsigned int cvt_pk_bf16(float lo, float hi) {
    unsigned int r;
    asm("v_cvt_pk_bf16_f32 %0, %1, %2" : "=v"(r) : "v"(lo), "v"(hi));
    return r;   // dst[15:0] = bf16(lo), dst[31:16] = bf16(hi)
}
// async global -> LDS, 16 B per lane; LDS dest = wave-uniform base + lane*16
typedef __attribute__((address_space(1))) const unsigned int  gu32;
typedef __attribute__((address_space(3))) unsigned int        lu32;
static __device__ __forceinline__ void g2l16(const unsigned short* g, unsigned short* l)
{
    __builtin_amdgcn_global_load_lds((gu32*)g, (lu32*)l, 16, 0, 0);
}

// ---------------------------------------------------------------- prep:
// bid < 8192: x -> bf16 cvt (8 floats/thread).
// bid 8192..8447: square 512x512 fp32->bf16 transpose, matrix = (bid-8192)>>6.
// bid 8448..8639: conv-weight 1536x512 fp32->bf16 transpose.
__global__ __launch_bounds__(256)
void prep(const float* __restrict__ x, unsigned short* __restrict__ xb,
          const float* __restrict__ Wq, const float* __restrict__ Wk,
          const float* __restrict__ Wv, const float* __restrict__ mw,
          unsigned short* __restrict__ WqT, unsigned short* __restrict__ WkT,
          unsigned short* __restrict__ WvT, unsigned short* __restrict__ CombT,
          const float* __restrict__ cw, unsigned short* __restrict__ ConvT)
{
    const int bid = blockIdx.x;
    const int t   = threadIdx.x;
    if (bid < 8192) {
        const size_t i = ((size_t)bid * 256 + t) * 8;
        const float4 a = *(const float4*)(x + i);
        const float4 b = *(const float4*)(x + i + 4);
        short8 o;
        o[0] = (short)f2bf(a.x); o[1] = (short)f2bf(a.y);
        o[2] = (short)f2bf(a.z); o[3] = (short)f2bf(a.w);
        o[4] = (short)f2bf(b.x); o[5] = (short)f2bf(b.y);
        o[6] = (short)f2bf(b.z); o[7] = (short)f2bf(b.w);
        *(short8*)(xb + i) = o;
        return;
    }
    __shared__ unsigned short T[64][72];
    const int tb = bid - 8192;
    const float* src; unsigned short* dst; int r0, c0, R;
    if (tb < 256) {
        const int m  = tb >> 6;
        const int xy = tb & 63;
        r0 = (xy >> 3) * 64; c0 = (xy & 7) * 64; R = 512;
        switch (m) {
            case 0:  src = Wq; dst = WqT;   break;
            case 1:  src = Wk; dst = WkT;   break;
            case 2:  src = Wv; dst = WvT;   break;
            default: src = mw; dst = CombT; break;
        }
    } else {
        const int t2 = tb - 256;             // 0..191
        c0 = (t2 & 7) * 64; r0 = (t2 >> 3) * 64; R = 1536;
        src = cw; dst = ConvT;
    }
    const int row = t >> 2, cg = (t & 3) * 16;
    const float* s = src + (size_t)(r0 + row) * 512 + c0 + cg;
    const float4 f0 = *(const float4*)s;
    const float4 f1 = *(const float4*)(s + 4);
    const float4 f2 = *(const float4*)(s + 8);
    const float4 f3 = *(const float4*)(s + 12);
    T[row][cg + 0]  = f2bf(f0.x); T[row][cg + 1]  = f2bf(f0.y);
    T[row][cg + 2]  = f2bf(f0.z); T[row][cg + 3]  = f2bf(f0.w);
    T[row][cg + 4]  = f2bf(f1.x); T[row][cg + 5]  = f2bf(f1.y);
    T[row][cg + 6]  = f2bf(f1.z); T[row][cg + 7]  = f2bf(f1.w);
    T[row][cg + 8]  = f2bf(f2.x); T[row][cg + 9]  = f2bf(f2.y);
    T[row][cg + 10] = f2bf(f2.z); T[row][cg + 11] = f2bf(f2.w);
    T[row][cg + 12] = f2bf(f3.x); T[row][cg + 13] = f2bf(f3.y);
    T[row][cg + 14] = f2bf(f3.z); T[row][cg + 15] = f2bf(f3.w);
    __syncthreads();
    unsigned short* d = dst + (size_t)(c0 + row) * R + r0 + cg;
    short8 o0, o1;
    #pragma unroll
    for (int k = 0; k < 8; ++k) o0[k] = (short)T[cg + k][row];
    #pragma unroll
    for (int k = 0; k < 8; ++k) o1[k] = (short)T[cg + 8 + k][row];
    *(short8*)d       = o0;
    *(short8*)(d + 8) = o1;
}

// ---------------------------------------------------------------- transpose bf16
__global__ __launch_bounds__(256)
void tr_bf16(unsigned short* __restrict__ dst, const unsigned short* __restrict__ src,
             int R, int C)
{
    __shared__ unsigned short T[64][72];
    const size_t bofs = (size_t)blockIdx.z * (size_t)R * (size_t)C;
    src += bofs; dst += bofs;
    const int t  = threadIdx.x;
    const int r0 = blockIdx.y * 64, c0 = blockIdx.x * 64;
    const int row = t >> 2, cg = (t & 3) * 16;
    const unsigned short* s = src + (size_t)(r0 + row) * C + c0 + cg;
    *(short8*)&T[row][cg]     = *(const short8*)s;
    *(short8*)&T[row][cg + 8] = *(const short8*)(s + 8);
    __syncthreads();
    unsigned short* d = dst + (size_t)(c0 + row) * R + r0 + cg;
    short8 o0, o1;
    #pragma unroll
    for (int k = 0; k < 8; ++k) o0[k] = (short)T[cg + k][row];
    #pragma unroll
    for (int k = 0; k < 8; ++k) o1[k] = (short)T[cg + 8 + k][row];
    *(short8*)d       = o0;
    *(short8*)(d + 8) = o1;
}

// ---------------------------------------------------------------- GEMM 128x128x32
// MODE 0: bf16 store. MODE 1: conv epilogue (+bias, ELU, MaxPool2 -> bf16).
// MODE 2: +bias, fp32 store. global_load_lds double-buffer (v10-verified).
template<int MODE>
__global__ __launch_bounds__(256)
void gemm128(const unsigned short* __restrict__ A, const unsigned short* __restrict__ Bt,
             const float* __restrict__ bias, void* __restrict__ Cout, int K)
{
    __shared__ unsigned short As[2][128 * 32];
    __shared__ unsigned short Bs[2][128 * 32];
    const int t    = threadIdx.x;
    const int n0   = blockIdx.x * 128;
    const int m0   = blockIdx.y * 128;
    const int lane = t & 63, wv = t >> 6;
    const int q = lane >> 4, ln = lane & 15;
    const int wm = (wv & 1) * 64, wn = (wv >> 1) * 64;

    const int srl = (wv << 5) + (lane >> 2);     // rows srl and srl+16
    const int scs = (lane & 3) * 8;              // 16B column (shorts)
    const unsigned short* arow0;
    const unsigned short* arow1;
    if (MODE == 1) {
        const int gr0 = m0 + srl;                // block never straddles a batch
        arow0 = A + (size_t)(gr0 >> 12) * PADROW + (size_t)(gr0 & 4095) * 512 + scs;
        arow1 = arow0 + (size_t)16 * 512;
    } else {
        arow0 = A + (size_t)(m0 + srl) * K + scs;
        arow1 = arow0 + (size_t)16 * K;
    }
    const unsigned short* brow0 = Bt + (size_t)(n0 + srl) * K + scs;
    const unsigned short* brow1 = brow0 + (size_t)16 * K;

    const int lb0 = (wv << 5) * 32;
    const int lb1 = lb0 + 16 * 32;

    const f32x4 zero = {0.f, 0.f, 0.f, 0.f};
    f32x4 acc[4][4];
    #pragma unroll
    for (int i = 0; i < 4; ++i)
        #pragma unroll
        for (int j = 0; j < 4; ++j) acc[i][j] = zero;

    g2l16(arow0, &As[0][lb0]);  g2l16(arow1, &As[0][lb1]);
    g2l16(brow0, &Bs[0][lb0]);  g2l16(brow1, &Bs[0][lb1]);

    for (int k0 = 0; k0 < K; k0 += 32) {
        const int cur = (k0 >> 5) & 1;
        __syncthreads();   // drains vmcnt: buf[cur] staged; prev reads done
        if (k0 + 32 < K) {
            const int nxt = cur ^ 1;
            g2l16(arow0 + k0 + 32, &As[nxt][lb0]);
            g2l16(arow1 + k0 + 32, &As[nxt][lb1]);
            g2l16(brow0 + k0 + 32, &Bs[nxt][lb0]);
            g2l16(brow1 + k0 + 32, &Bs[nxt][lb1]);
        }
        short8 af[4], bf[4];
        #pragma unroll
        for (int mt = 0; mt < 4; ++mt)
            af[mt] = *(const short8*)&As[cur][(wm + mt * 16 + ln) * 32 + q * 8];
        #pragma unroll
        for (int nt = 0; nt < 4; ++nt)
            bf[nt] = *(const short8*)&Bs[cur][(wn + nt * 16 + ln) * 32 + q * 8];
        #pragma unroll
        for (int mt = 0; mt < 4; ++mt)
            #pragma unroll
            for (int nt = 0; nt < 4; ++nt)
                acc[mt][nt] = __builtin_amdgcn_mfma_f32_16x16x32_bf16(af[mt], bf[nt], acc[mt][nt], 0, 0, 0);
    }

    if (MODE == 0) {
        unsigned short* C = (unsigned short*)Cout;
        #pragma unroll
        for (int mt = 0; mt < 4; ++mt)
            #pragma unroll
            for (int r = 0; r < 4; ++r) {
                const int grow = m0 + wm + mt * 16 + q * 4 + r;
                unsigned short* cp = C + (size_t)grow * 512 + n0 + wn + ln;
                #pragma unroll
                for (int nt = 0; nt < 4; ++nt) cp[nt * 16] = f2bf(acc[mt][nt][r]);
            }
    } else if (MODE == 2) {
        float* C = (float*)Cout;
        float bb[4];
        #pragma unroll
        for (int nt = 0; nt < 4; ++nt) bb[nt] = bias[n0 + wn + nt * 16 + ln];
        #pragma unroll
        for (int mt = 0; mt < 4; ++mt)
            #pragma unroll
            for (int r = 0; r < 4; ++r) {
                const int grow = m0 + wm + mt * 16 + q * 4 + r;
                float* cp = C + (size_t)grow * 512 + n0 + wn + ln;
                #pragma unroll
                for (int nt = 0; nt < 4; ++nt) cp[nt * 16] = acc[mt][nt][r] + bb[nt];
            }
    } else { // MODE 1
        unsigned short* C = (unsigned short*)Cout;
        float bb[4];
        #pragma unroll
        for (int nt = 0; nt < 4; ++nt) bb[nt] = bias[n0 + wn + nt * 16 + ln];
        #pragma unroll
        for (int mt = 0; mt < 4; ++mt) {
            const int grow = m0 + wm + mt * 16 + q * 4;
            const int b = grow >> 12, l = grow & 4095;
            unsigned short* cp = C + ((size_t)b * 2048 + (l >> 1)) * 512 + n0 + wn + ln;
            #pragma unroll
            for (int nt = 0; nt < 4; ++nt) {
                float v0 = acc[mt][nt][0] + bb[nt]; v0 = v0 > 0.f ? v0 : __expf(v0) - 1.f;
                float v1 = acc[mt][nt][1] + bb[nt]; v1 = v1 > 0.f ? v1 : __expf(v1) - 1.f;
                float v2 = acc[mt][nt][2] + bb[nt]; v2 = v2 > 0.f ? v2 : __expf(v2) - 1.f;
                float v3 = acc[mt][nt][3] + bb[nt]; v3 = v3 > 0.f ? v3 : __expf(v3) - 1.f;
                cp[nt * 16]       = f2bf(fmaxf(v0, v1));
                cp[512 + nt * 16] = f2bf(fmaxf(v2, v3));
            }
        }
    }
}

// ---------------------------------------------------------------- fused gather + K/V projection
// grid (4, 32, 2): z=0 K-proj (pv index chain, B=WkT, C=Kg); z=1 V-proj
// (qv chain, B=WvT, C=Vg). Identical GEMM body to gemm128 MODE 0, but the
// A rows are read from xb through the sidx indirection (exact gather_rows
// clip semantics).
__global__ __launch_bounds__(256)
void gemm_proj(const unsigned short* __restrict__ xb, const int* __restrict__ sidx,
               const unsigned short* __restrict__ WkT, const unsigned short* __restrict__ WvT,
               unsigned short* __restrict__ Kg, unsigned short* __restrict__ Vg)
{
    __shared__ unsigned short As[2][128 * 32];
    __shared__ unsigned short Bs[2][128 * 32];
    const int K    = 512;
    const int t    = threadIdx.x;
    const int z    = blockIdx.z;
    const int n0   = blockIdx.x * 128;
    const int m0   = blockIdx.y * 128;
    const int lane = t & 63, wv = t >> 6;
    const int q = lane >> 4, ln = lane & 15;
    const int wm = (wv & 1) * 64, wn = (wv >> 1) * 64;

    const unsigned short* Bt = z == 0 ? WkT : WvT;
    unsigned short* C        = z == 0 ? Kg  : Vg;

    const int srl = (wv << 5) + (lane >> 2);
    const int scs = (lane & 3) * 8;
    // gathered-row indirection (gather_rows semantics, bit-identical)
    const unsigned short* arow[2];
    #pragma unroll
    for (int i = 0; i < 2; ++i) {
        const int gr = m0 + srl + i * 16;        // in [0, 4096)
        const int b = gr >> 9, j = gr & 511;
        int qv = sidx[j];  qv = qv < 0 ? 0 : (qv > LSEQ - 1 ? LSEQ - 1 : qv);
        int idx = qv;
        if (z == 0) {
            const int cv = qv < SK - 1 ? qv : SK - 1;
            int pv = sidx[cv];  pv = pv < 0 ? 0 : (pv > LSEQ - 1 ? LSEQ - 1 : pv);
            idx = pv;
        }
        arow[i] = xb + ((size_t)b * LSEQ + idx) * 512 + scs;
    }
    const unsigned short* brow0 = Bt + (size_t)(n0 + srl) * K + scs;
    const unsigned short* brow1 = brow0 + (size_t)16 * K;

    const int lb0 = (wv << 5) * 32;
    const int lb1 = lb0 + 16 * 32;

    const f32x4 zero = {0.f, 0.f, 0.f, 0.f};
    f32x4 acc[4][4];
    #pragma unroll
    for (int i = 0; i < 4; ++i)
        #pragma unroll
        for (int j = 0; j < 4; ++j) acc[i][j] = zero;

    g2l16(arow[0], &As[0][lb0]);  g2l16(arow[1], &As[0][lb1]);
    g2l16(brow0, &Bs[0][lb0]);    g2l16(brow1, &Bs[0][lb1]);

    for (int k0 = 0; k0 < K; k0 += 32) {
        const int cur = (k0 >> 5) & 1;
        __syncthreads();
        if (k0 + 32 < K) {
            const int nxt = cur ^ 1;
            g2l16(arow[0] + k0 + 32, &As[nxt][lb0]);
            g2l16(arow[1] + k0 + 32, &As[nxt][lb1]);
            g2l16(brow0 + k0 + 32, &Bs[nxt][lb0]);
            g2l16(brow1 + k0 + 32, &Bs[nxt][lb1]);
        }
        short8 af[4], bf[4];
        #pragma unroll
        for (int mt = 0; mt < 4; ++mt)
            af[mt] = *(const short8*)&As[cur][(wm + mt * 16 + ln) * 32 + q * 8];
        #pragma unroll
        for (int nt = 0; nt < 4; ++nt)
            bf[nt] = *(const short8*)&Bs[cur][(wn + nt * 16 + ln) * 32 + q * 8];
        #pragma unroll
        for (int mt = 0; mt < 4; ++mt)
            #pragma unroll
            for (int nt = 0; nt < 4; ++nt)
                acc[mt][nt] = __builtin_amdgcn_mfma_f32_16x16x32_bf16(af[mt], bf[nt], acc[mt][nt], 0, 0, 0);
    }

    #pragma unroll
    for (int mt = 0; mt < 4; ++mt)
        #pragma unroll
        for (int r = 0; r < 4; ++r) {
            const int grow = m0 + wm + mt * 16 + q * 4 + r;
            unsigned short* cp = C + (size_t)grow * 512 + n0 + wn + ln;
            #pragma unroll
            for (int nt = 0; nt < 4; ++nt) cp[nt * 16] = f2bf(acc[mt][nt][r]);
        }
}

// ---------------------------------------------------------------- fused attention v9 (+pad init)
// grid (L/128, H, B), 256 threads = 4 waves; wave w owns 32 q-rows (2 tiles).
// Blocks (x==0, h==0) additionally zero batch b's two pad rows (legal here:
// runs after tr_bf16 consumed the Vg alias; conv reads after attn ends).
__global__ __launch_bounds__(256, 2)
void attn_fused(const unsigned short* __restrict__ xb, const unsigned short* __restrict__ WqT,
                const unsigned short* __restrict__ Kg, const unsigned short* __restrict__ Vt,
                unsigned short* __restrict__ attpad)
{
    __shared__ unsigned short Ks[128][72];
    __shared__ unsigned short Vs[64][136];
    __shared__ unsigned short Pp[128][136];   // P per chunk; also Q round-trip
    const int t = threadIdx.x;
    const int wv = t >> 6, lane = t & 63, q = lane >> 4, ln = lane & 15;
    const int l0 = blockIdx.x * 128, h = blockIdx.y, b = blockIdx.z;
    const int qr0 = wv * 32;
    const f32x4 zero = {0.f, 0.f, 0.f, 0.f};

    // pad-row init (was zero_pad kernel): 256 threads x 1 u32 = 512 shorts/row
    if (blockIdx.x == 0 && h == 0) {
        unsigned int* p0 = (unsigned int*)(attpad + (size_t)b * PADROW);
        unsigned int* p1 = (unsigned int*)(attpad + (size_t)b * PADROW + (size_t)(LPAD - 1) * 512);
        p0[t] = 0u;  p1[t] = 0u;
    }

    // staging maps
    const unsigned short* kgb = Kg + (size_t)b * SK * 512 + h * 64;        // + s*512 + e
    const unsigned short* vtb = Vt + ((size_t)(b * EDIM + h * 64)) * SK;   // + d*SK + s
    const int ksr = t >> 1, ksc = (t & 1) * 32;    // K: row s, 32-short half
    const int vsr = t >> 2, vsc = (t & 3) * 32;    // V: row d, 32-short quarter

    // prefetch chunk 0 (flies during Q projection)
    short8 kp0, kp1, kp2, kp3, vp0, vp1, vp2, vp3;
    {
        const unsigned short* ks = kgb + (size_t)ksr * 512 + ksc;
        kp0 = *(const short8*)ks;        kp1 = *(const short8*)(ks + 8);
        kp2 = *(const short8*)(ks + 16); kp3 = *(const short8*)(ks + 24);
        const unsigned short* vs = vtb + (size_t)vsr * SK + vsc;
        vp0 = *(const short8*)vs;        vp1 = *(const short8*)(vs + 8);
        vp2 = *(const short8*)(vs + 16); vp3 = *(const short8*)(vs + 24);
    }

    // --- Q projection: rows qr0 + g*16 + ln (g=0,1), 64 head cols, k=512
    f32x4 qacc[2][4];
    #pragma unroll
    for (int g = 0; g < 2; ++g)
        #pragma unroll
        for (int nt = 0; nt < 4; ++nt) qacc[g][nt] = zero;
    const unsigned short* xr0 = xb + ((size_t)(b * LSEQ + l0 + qr0 + ln)) * 512 + q * 8;
    const unsigned short* xr1 = xr0 + (size_t)16 * 512;
    const unsigned short* wqp = WqT + ((size_t)(h * 64 + ln)) * 512 + q * 8;
    for (int ks = 0; ks < 16; ++ks) {
        const short8 ax0 = *(const short8*)(xr0 + ks * 32);
        const short8 ax1 = *(const short8*)(xr1 + ks * 32);
        #pragma unroll
        for (int nt = 0; nt < 4; ++nt) {
            const short8 bw = *(const short8*)(wqp + nt * 16 * 512 + ks * 32);
            qacc[0][nt] = __builtin_amdgcn_mfma_f32_16x16x32_bf16(ax0, bw, qacc[0][nt], 0, 0, 0);
            qacc[1][nt] = __builtin_amdgcn_mfma_f32_16x16x32_bf16(ax1, bw, qacc[1][nt], 0, 0, 0);
        }
    }
    #pragma unroll
    for (int g = 0; g < 2; ++g)
        #pragma unroll
        for (int nt = 0; nt < 4; ++nt)
            #pragma unroll
            for (int r = 0; r < 4; ++r)
                Pp[qr0 + g * 16 + q * 4 + r][nt * 16 + ln] = f2bf(qacc[g][nt][r]);
    asm volatile("s_waitcnt lgkmcnt(0)" ::: "memory");   // wave-private round trip
    short8 bq[2][2];
    #pragma unroll
    for (int g = 0; g < 2; ++g) {
        bq[g][0] = *(const short8*)&Pp[qr0 + g * 16 + ln][q * 8];
        bq[g][1] = *(const short8*)&Pp[qr0 + g * 16 + ln][q * 8 + 32];
    }

    // --- flash state in base-2 domain (per q-col = ln, per group g)
    float m_run[2] = {-1e30f, -1e30f}, l_run[2] = {0.f, 0.f};
    f32x4 o[2][4];
    #pragma unroll
    for (int g = 0; g < 2; ++g)
        #pragma unroll
        for (int j = 0; j < 4; ++j) o[g][j] = zero;

    for (int c = 0; c < 4; ++c) {
        // store staged chunk (regs were prefetched)
        *(short8*)&Ks[ksr][ksc]      = kp0;  *(short8*)&Ks[ksr][ksc + 8]  = kp1;
        *(short8*)&Ks[ksr][ksc + 16] = kp2;  *(short8*)&Ks[ksr][ksc + 24] = kp3;
        *(short8*)&Vs[vsr][vsc]      = vp0;  *(short8*)&Vs[vsr][vsc + 8]  = vp1;
        *(short8*)&Vs[vsr][vsc + 16] = vp2;  *(short8*)&Vs[vsr][vsc + 24] = vp3;
        __syncthreads();   // A: Ks/Vs ready

        // scores (transposed, pre-scaled by 0.125*log2e):
        // St[s = mt*16+quad*4+r][qcol = g*16+ln]
        f32x4 st[8][2];
        #pragma unroll
        for (int mt = 0; mt < 8; ++mt) {
            const short8 ak0 = *(const short8*)&Ks[mt * 16 + ln][q * 8];
            const short8 ak1 = *(const short8*)&Ks[mt * 16 + ln][q * 8 + 32];
            #pragma unroll
            for (int g = 0; g < 2; ++g) {
                f32x4 a = zero;
                a = __builtin_amdgcn_mfma_f32_16x16x32_bf16(ak0, bq[g][0], a, 0, 0, 0);
                a = __builtin_amdgcn_mfma_f32_16x16x32_bf16(ak1, bq[g][1], a, 0, 0, 0);
                #pragma unroll
                for (int r = 0; r < 4; ++r) a[r] *= SCALE2;
                st[mt][g] = a;
            }
        }

        // online softmax (base-2): max, alpha, exp2 + cvt_pk pack, l fold
        float alpha_[2];
        #pragma unroll
        for (int g = 0; g < 2; ++g) {
            float mx = st[0][g][0];
            #pragma unroll
            for (int mt = 0; mt < 8; ++mt)
                #pragma unroll
                for (int r = 0; r < 4; ++r) mx = fmaxf(mx, st[mt][g][r]);
            mx = fmaxf(mx, __shfl_xor(mx, 16));
            mx = fmaxf(mx, __shfl_xor(mx, 32));
            const float m_new = fmaxf(m_run[g], mx);
            alpha_[g] = __builtin_amdgcn_exp2f(m_run[g] - m_new);
            m_run[g] = m_new;
            float ls = 0.f;
            #pragma unroll
            for (int mt = 0; mt < 8; ++mt) {
                const float p0 = __builtin_amdgcn_exp2f(st[mt][g][0] - m_new);
                const float p1 = __builtin_amdgcn_exp2f(st[mt][g][1] - m_new);
                const float p2 = __builtin_amdgcn_exp2f(st[mt][g][2] - m_new);
                const float p3 = __builtin_amdgcn_exp2f(st[mt][g][3] - m_new);
                ls += (p0 + p1) + (p2 + p3);
                uint2 pw;
                pw.x = cvt_pk_bf16(p0, p1);
                pw.y = cvt_pk_bf16(p2, p3);
                *(uint2*)&Pp[qr0 + g * 16 + ln][mt * 16 + q * 4] = pw;
            }
            ls += __shfl_xor(ls, 16);
            ls += __shfl_xor(ls, 32);
            l_run[g] = l_run[g] * alpha_[g] + ls;
        }

        // rescale O (rows q' = quad*4+r of tile g)
        #pragma unroll
        for (int g = 0; g < 2; ++g) {
            #pragma unroll
            for (int r = 0; r < 4; ++r) {
                const float ab = __shfl(alpha_[g], q * 4 + r);
                #pragma unroll
                for (int j = 0; j < 4; ++j) o[g][j][r] *= ab;
            }
        }

        // prefetch next chunk into regs (overlaps PV)
        if (c < 3) {
            const unsigned short* ks = kgb + (size_t)((c + 1) * 128 + ksr) * 512 + ksc;
            kp0 = *(const short8*)ks;        kp1 = *(const short8*)(ks + 8);
            kp2 = *(const short8*)(ks + 16); kp3 = *(const short8*)(ks + 24);
            const unsigned short* vs = vtb + (size_t)vsr * SK + (c + 1) * 128 + vsc;
            vp0 = *(const short8*)vs;        vp1 = *(const short8*)(vs + 8);
            vp2 = *(const short8*)(vs + 16); vp3 = *(const short8*)(vs + 24);
        }

        asm volatile("s_waitcnt lgkmcnt(0)" ::: "memory");   // P visible to wave

        // PV: A = P rows (q), B = Vs rows (d), k = 128 chunk
        #pragma unroll
        for (int ks2 = 0; ks2 < 4; ++ks2) {
            const short8 ap0 = *(const short8*)&Pp[qr0 + ln][ks2 * 32 + q * 8];
            const short8 ap1 = *(const short8*)&Pp[qr0 + 16 + ln][ks2 * 32 + q * 8];
            #pragma unroll
            for (int j = 0; j < 4; ++j) {
                const short8 bv = *(const short8*)&Vs[j * 16 + ln][ks2 * 32 + q * 8];
                o[0][j] = __builtin_amdgcn_mfma_f32_16x16x32_bf16(ap0, bv, o[0][j], 0, 0, 0);
                o[1][j] = __builtin_amdgcn_mfma_f32_16x16x32_bf16(ap1, bv, o[1][j], 0, 0, 0);
            }
        }
        __syncthreads();   // B: Ks/Vs reads done before restage
    }

    // epilogue: scale by 1/l, store rows l0+qr0+g*16+q*4+r (+1 pad offset)
    #pragma unroll
    for (int g = 0; g < 2; ++g) {
        const float li = 1.f / l_run[g];
        #pragma unroll
        for (int r = 0; r < 4; ++r) {
            const float ib = __shfl(li, q * 4 + r);
            const int rl = qr0 + g * 16 + q * 4 + r;
            #pragma unroll
            for (int j = 0; j < 4; ++j)
                attpad[((size_t)b * PADROW) + (size_t)(l0 + rl + 1) * 512 + h * 64 + j * 16 + ln]
                    = f2bf(o[g][j][r] * ib);
        }
    }
}

// ---------------------------------------------------------------- launcher
extern "C" void kernel_launch(void* const* d_in, const int* in_sizes, int n_in,
                              void* d_out, int out_size, void* d_ws, size_t ws_size,
                              hipStream_t stream)
{
    const float* x    = (const float*)d_in[0];
    const float* Wq   = (const float*)d_in[1];
    const float* Wk   = (const float*)d_in[2];
    const float* Wv   = (const float*)d_in[3];
    const float* cw   = (const float*)d_in[4];   // [1536][512] flat fp32
    const float* cb   = (const float*)d_in[5];
    const float* mw   = (const float*)d_in[6];
    const float* mb2  = (const float*)d_in[7];
    const int*   sidx = (const int*)d_in[8];
    float* out = (float*)d_out;

    char* ws = (char*)d_ws;
    unsigned short* xb    = (unsigned short*)(ws + 0);           // 33,554,432 B
    unsigned short* Pool  = (unsigned short*)(ws + 0);           // alias (xb dead post-attn)
    unsigned short* Pad   = (unsigned short*)(ws + 33554432);    // 33,570,816 B
    unsigned short* Vg    = (unsigned short*)(ws + 41943040);    // alias Pad interior (dead pre-attn)
    unsigned short* Kg    = (unsigned short*)(ws + 67125248);    //  4,194,304 B
    unsigned short* Vt    = (unsigned short*)(ws + 71319552);    //  4,194,304 B
    unsigned short* WqT   = (unsigned short*)(ws + 75513856);    //    524,288 B
    unsigned short* WkT   = (unsigned short*)(ws + 76038144);
    unsigned short* WvT   = (unsigned short*)(ws + 76562432);
    unsigned short* CombT = (unsigned short*)(ws + 77086720);
    unsigned short* ConvT = (unsigned short*)(ws + 77611008);    // 1,572,864 B -> end 79,183,872

    dim3 blk(256);

    // 0. prep: x->bf16 + all 5 weight transposes (one dispatch)
    prep<<<dim3(8640), blk, 0, stream>>>(x, xb, Wq, Wk, Wv, mw,
                                         WqT, WkT, WvT, CombT, cw, ConvT);

    // 1. fused gather + K/V projections (z=0: K via pv; z=1: V via qv)
    gemm_proj<<<dim3(4, 32, 2), blk, 0, stream>>>(xb, sidx, WkT, WvT, Kg, Vg);

    // 2. Vt[b][e][s] = Vg[b][s][e]
    tr_bf16<<<dim3(8, 8, 8), blk, 0, stream>>>(Vt, Vg, 512, 512);

    // 3. attention (M=128 flash; also zeroes Pad boundary rows; writes rows 1..L)
    attn_fused<<<dim3(32, 8, 8), blk, 0, stream>>>(xb, WqT, Kg, Vt, Pad);

    // 4. conv (K=1536) + bias + ELU + pool -> Pool (aliases dead xb)
    gemm128<1><<<dim3(4, 256), blk, 0, stream>>>(Pad, ConvT, cb, Pool, 1536);

    // 5. final dense + bias -> out (fp32)
    gemm128<2><<<dim3(4, 128), blk, 0, stream>>>(Pool, CombT, mb2, out, 512);
}